// Round 5
// baseline (177.875 us; speedup 1.0000x reference)
//
#include <hip/hip_runtime.h>
#include <math.h>

#define NN 1000000
#define NF4 5000000       // NN*5 float4s in Memory
#define WD 20
#define NB 977            // blocks of 1024 rows
#define PST 1024          // pnrhT column stride

// d_out layout (floats): out[325] | rw[NN] | ww[NN] | new_memory[NN*20] | nrh[20]
#define OUT_OFF 0
#define RW_OFF  325
#define WW_OFF  1000325
#define NM_OFF  2000325
#define NRH_OFF 22000325

__device__ __forceinline__ float sigmoidf_(float x){ return 1.0f/(1.0f+expf(-x)); }
__device__ __forceinline__ float softplusf_(float x){ return (x>30.f)?x:log1pf(expf(x)); }

// ------- K1: controller-head prologue (redundant per block) + cosine scores -------
// P layout: kr:0-19 gr:20 sr:21-23 gammar:24 betar:25 knr:26
//           kw:32-51 gw:52 sw:53-55 gammaw:56 betaw:57 knw:58
//           erase:64-83 addraw:84-103 rho:104 ah0:105 ah1:106 addf:112-131
__global__ __launch_bounds__(256) void k_scores(
    const float* __restrict__ X,
    const float* __restrict__ W1, const float* __restrict__ b1,
    const float* __restrict__ W2, const float* __restrict__ b2,
    const float* __restrict__ Wxi, const float* __restrict__ bxi,
    const float* __restrict__ Wz, const float* __restrict__ bz,
    const float* __restrict__ M, float* __restrict__ Pg,
    float2* __restrict__ sc2, float4* __restrict__ pms){
  __shared__ float4 ld[1280];   // 20 KB
  __shared__ float h1[48], h2[72], xi[95], sP[132];
  int t=threadIdx.x, b=blockIdx.x;
  // --- head prologue (identical in every block; block 0 publishes) ---
  if(t<48){ float a=b1[t]; const float* w=W1+t*14; for(int c=0;c<14;c++) a+=X[c]*w[c]; h1[t]=a; }
  __syncthreads();
  if(t<72){ float a=b2[t]; const float* w=W2+t*48; for(int c=0;c<48;c++) a+=h1[c]*w[c]; h2[t]=a; }
  __syncthreads();
  if(t<92){ float a=bxi[t]; const float* w=Wxi+t*72; for(int c=0;c<72;c++) a+=h2[c]*w[c]; xi[t]=a; }
  else if(t<95){ int z=t-92; float a=bz[z]; const float* w=Wz+z*72; for(int c=0;c<72;c++) a+=h2[c]*w[c]; xi[92+z]=a; }
  __syncthreads();
  if(t<20){
    sP[0+t]  = tanhf(xi[t]);
    sP[32+t] = tanhf(xi[26+t]);
    sP[64+t] = sigmoidf_(xi[52+t]);
    sP[84+t] = tanhf(xi[72+t]);
  }
  __syncthreads();
  if(t==32){   // read-head scalars (wave 0); norm from already-computed tanh in sP
    float g=sigmoidf_(xi[20]);
    float a0=xi[21],a1=xi[22],a2=xi[23];
    float mx=fmaxf(a0,fmaxf(a1,a2));
    float e0=expf(a0-mx),e1=expf(a1-mx),e2=expf(a2-mx),es=e0+e1+e2;
    float gamma=1.0f+softplusf_(xi[24]);
    float beta=softplusf_(xi[25]);
    float n2=0.f;
#pragma unroll
    for(int j=0;j<20;j++){ float ke=sP[j]+1e-16f; n2+=ke*ke; }
    sP[20]=g; sP[21]=e0/es; sP[22]=e1/es; sP[23]=e2/es; sP[24]=gamma; sP[25]=beta;
    sP[26]=fmaxf(sqrtf(n2),1e-8f);
  }
  if(t==96){   // write-head scalars (wave 1)
    float g=sigmoidf_(xi[46]);
    float a0=xi[47],a1=xi[48],a2=xi[49];
    float mx=fmaxf(a0,fmaxf(a1,a2));
    float e0=expf(a0-mx),e1=expf(a1-mx),e2=expf(a2-mx),es=e0+e1+e2;
    float gamma=1.0f+softplusf_(xi[50]);
    float beta=softplusf_(xi[51]);
    float n2=0.f;
#pragma unroll
    for(int j=0;j<20;j++){ float ke=sP[32+j]+1e-16f; n2+=ke*ke; }
    sP[52]=g; sP[53]=e0/es; sP[54]=e1/es; sP[55]=e2/es; sP[56]=gamma; sP[57]=beta;
    sP[58]=fmaxf(sqrtf(n2),1e-8f);
  }
  if(t==160){  // zeta scalars (wave 2)
    sP[104]=sigmoidf_(xi[92]);
    float mx=fmaxf(xi[93],xi[94]);
    float e1=expf(xi[93]-mx), e2=expf(xi[94]-mx);
    sP[105]=e1/(e1+e2); sP[106]=e2/(e1+e2);
  }
  __syncthreads();
  if(b==0 && t<132) Pg[t]=sP[t];
  float kr[20], kw[20];
#pragma unroll
  for(int j=0;j<20;j++){ kr[j]=sP[j]+1e-16f; kw[j]=sP[32+j]+1e-16f; }
  float betar=sP[25], betaw=sP[57], knr=sP[26], knw=sP[58];
  // --- streaming scores ---
  const float4* Mf4=(const float4*)M;
  float sR[4], sW[4];
  for(int p=0;p<4;p++){
    int rb=b*1024+p*256;
    size_t f4b=(size_t)rb*5;
#pragma unroll
    for(int k=0;k<5;k++){
      size_t idx=f4b+(size_t)(k*256+t);
      ld[k*256+t] = (idx<NF4)?Mf4[idx]:make_float4(0.f,0.f,0.f,0.f);
    }
    __syncthreads();
    int i=rb+t;
    float srv=-3.0e38f, swv=-3.0e38f;
    if(i<NN){
      float dr=0.f,dw=0.f,n2=0.f;
#pragma unroll
      for(int q=0;q<5;q++){
        float4 v=ld[t*5+q];
        float m0=v.x+1e-16f,m1=v.y+1e-16f,m2=v.z+1e-16f,m3=v.w+1e-16f;
        dr+=m0*kr[4*q]+m1*kr[4*q+1]+m2*kr[4*q+2]+m3*kr[4*q+3];
        dw+=m0*kw[4*q]+m1*kw[4*q+1]+m2*kw[4*q+2]+m3*kw[4*q+3];
        n2+=m0*m0+m1*m1+m2*m2+m3*m3;
      }
      float nm=fmaxf(sqrtf(n2),1e-8f);
      srv=betar*(dr/(nm*knr));
      swv=betaw*(dw/(nm*knw));
      sc2[i]=make_float2(srv,swv);
    }
    sR[p]=srv; sW[p]=swv;
    __syncthreads();
  }
  // reductions (reuse ld as scratch)
  float* r1=(float*)ld; float* r2=r1+256;
  double* d1=(double*)(r1+512); double* d2=d1+256;
  float lm1=fmaxf(fmaxf(sR[0],sR[1]),fmaxf(sR[2],sR[3]));
  float lm2=fmaxf(fmaxf(sW[0],sW[1]),fmaxf(sW[2],sW[3]));
  r1[t]=lm1; r2[t]=lm2; __syncthreads();
  for(int o=128;o>0;o>>=1){ if(t<o){ r1[t]=fmaxf(r1[t],r1[t+o]); r2[t]=fmaxf(r2[t],r2[t+o]); } __syncthreads(); }
  float mb1=r1[0], mb2=r2[0]; __syncthreads();
  double s1=0.0,s2=0.0;
#pragma unroll
  for(int p=0;p<4;p++){ s1+=(double)expf(sR[p]-mb1); s2+=(double)expf(sW[p]-mb2); }
  d1[t]=s1; d2[t]=s2; __syncthreads();
  for(int o=128;o>0;o>>=1){ if(t<o){ d1[t]+=d1[t+o]; d2[t]+=d2[t+o]; } __syncthreads(); }
  if(t==0) pms[b]=make_float4(mb1,mb2,(float)d1[0],(float)d2[0]);
}

// ------- K2: interpolate+shift+pow; Z partials; fused rw@M (LDS-transposed) -------
__global__ __launch_bounds__(256) void k_shift(const float2* __restrict__ sc2,
                        const float* __restrict__ wpr, const float* __restrict__ wpw,
                        const float* __restrict__ M, const float* __restrict__ P,
                        const float4* __restrict__ pms,
                        float* __restrict__ w_r_out, float* __restrict__ w_w_out,
                        double* __restrict__ pZ, double* __restrict__ pnrhT){
  __shared__ float4 ld[1280];
  __shared__ float bmS[4];
  float* r1=(float*)ld; float* r2=r1+256;
  double* d1=(double*)(r1+512); double* d2=d1+256;
  float* wsum=(float*)(d2+256);  // [4][20]
  int t=threadIdx.x, b=blockIdx.x;
  // redundant global (m,S) reduction over NB partials
  float4 v4[4];
#pragma unroll
  for(int k=0;k<4;k++){
    int idx=t+k*256;
    v4[k] = (idx<NB) ? pms[idx] : make_float4(-3.0e38f,-3.0e38f,0.f,0.f);
  }
  float lm1=fmaxf(fmaxf(v4[0].x,v4[1].x),fmaxf(v4[2].x,v4[3].x));
  float lm2=fmaxf(fmaxf(v4[0].y,v4[1].y),fmaxf(v4[2].y,v4[3].y));
  r1[t]=lm1; r2[t]=lm2; __syncthreads();
  for(int o=128;o>0;o>>=1){ if(t<o){ r1[t]=fmaxf(r1[t],r1[t+o]); r2[t]=fmaxf(r2[t],r2[t+o]); } __syncthreads(); }
  if(t==0){ bmS[0]=r1[0]; bmS[1]=r2[0]; } __syncthreads();
  float mr=bmS[0], mw=bmS[1];
  double s1=0.0,s2=0.0;
#pragma unroll
  for(int k=0;k<4;k++){
    s1 += (double)v4[k].z * (double)expf(v4[k].x-mr);
    s2 += (double)v4[k].w * (double)expf(v4[k].y-mw);
  }
  d1[t]=s1; d2[t]=s2; __syncthreads();
  for(int o=128;o>0;o>>=1){ if(t<o){ d1[t]+=d1[t+o]; d2[t]+=d2[t+o]; } __syncthreads(); }
  if(t==0){ bmS[2]=(float)d1[0]; bmS[3]=(float)d2[0]; } __syncthreads();
  float Sr=bmS[2], Sw=bmS[3];
  float gr=P[20], s0r=P[21], s1r=P[22], s2r=P[23], gar=P[24];
  float gw=P[52], s0w=P[53], s1w=P[54], s2w=P[55], gaw=P[56];
  float omgr=1.0f-gr, omgw=1.0f-gw;
  const float4* Mf4=(const float4*)M;
  float acc[20];
#pragma unroll
  for(int j=0;j<20;j++) acc[j]=0.f;
  double zr=0.0, zw=0.0;
  for(int p=0;p<4;p++){
    int rb=b*1024+p*256;
    size_t f4b=(size_t)rb*5;
#pragma unroll
    for(int k=0;k<5;k++){
      size_t idx=f4b+(size_t)(k*256+t);
      ld[k*256+t] = (idx<NF4)?Mf4[idx]:make_float4(0.f,0.f,0.f,0.f);
    }
    __syncthreads();
    int i=rb+t;
    if(i<NN){
      int im1=(i==0)?(NN-1):(i-1);
      int ip1=(i==NN-1)?0:(i+1);
      float2 scm=sc2[im1], sc0=sc2[i], scp=sc2[ip1];
      float wgrm = gr*(expf(scm.x-mr)/Sr) + omgr*wpr[im1];
      float wgr0 = gr*(expf(sc0.x-mr)/Sr) + omgr*wpr[i  ];
      float wgrp = gr*(expf(scp.x-mr)/Sr) + omgr*wpr[ip1];
      float wgwm = gw*(expf(scm.y-mw)/Sw) + omgw*wpw[im1];
      float wgw0 = gw*(expf(sc0.y-mw)/Sw) + omgw*wpw[i  ];
      float wgwp = gw*(expf(scp.y-mw)/Sw) + omgw*wpw[ip1];
      float wr = powf(s0r*wgrm + s1r*wgr0 + s2r*wgrp, gar);
      float ww = powf(s0w*wgwm + s1w*wgw0 + s2w*wgwp, gaw);
      w_r_out[i]=wr; w_w_out[i]=ww;
      zr+=(double)wr; zw+=(double)ww;
#pragma unroll
      for(int q=0;q<5;q++){
        float4 mv=ld[t*5+q];
        acc[4*q+0]+=wr*mv.x; acc[4*q+1]+=wr*mv.y; acc[4*q+2]+=wr*mv.z; acc[4*q+3]+=wr*mv.w;
      }
    }
    __syncthreads();
  }
  d1[t]=zr; d2[t]=zw; __syncthreads();
  for(int o=128;o>0;o>>=1){ if(t<o){ d1[t]+=d1[t+o]; d2[t]+=d2[t+o]; } __syncthreads(); }
  if(t==0){ pZ[2*b]=d1[0]; pZ[2*b+1]=d2[0]; }
  __syncthreads();
#pragma unroll
  for(int j=0;j<20;j++){
    for(int off=32;off>0;off>>=1) acc[j]+=__shfl_down(acc[j],off,64);
  }
  int wave=t>>6, lane=t&63;
  if(lane==0){
#pragma unroll
    for(int j=0;j<20;j++) wsum[wave*20+j]=acc[j];
  }
  __syncthreads();
  if(t<20){
    double s=(double)wsum[0*20+t]+(double)wsum[1*20+t]+(double)wsum[2*20+t]+(double)wsum[3*20+t];
    pnrhT[(size_t)t*PST+b]=s;
  }
}

// ------- K3: merged {Z/nrh reduce + L1 + L2 (redundant), L3 split} -------
__global__ __launch_bounds__(512) void k_mlpA(
    const double* __restrict__ pZ, const double* __restrict__ pnrhT,
    const float* __restrict__ read_head,
    const float* __restrict__ aW1,const float* __restrict__ ab1,
    const float* __restrict__ mW1,const float* __restrict__ mb1,
    const float* __restrict__ aW2,const float* __restrict__ ab2,
    const float* __restrict__ mW2,const float* __restrict__ mb2,
    const float* __restrict__ aW3,const float* __restrict__ ab3,
    const float* __restrict__ mW3,const float* __restrict__ mb3,
    float* __restrict__ out, double* __restrict__ Sd, float* __restrict__ h3g){
  __shared__ float in40[40], h1s[220], h2s[380];
  __shared__ double nrhd[20], bZ[2];
  int t=threadIdx.x, b=blockIdx.x, wave=t>>6, lane=t&63;
  // pZ reduce (waves 0,1) — redundant in every block
  if(wave<2){
    double s=0.0;
    for(int idx=lane; idx<NB; idx+=64) s+=pZ[2*idx+wave];
    for(int off=32;off>0;off>>=1) s+=__shfl_down(s,off,64);
    if(lane==0) bZ[wave]=s;
  }
  // pnrhT columns (rows j strided over 8 waves)
  for(int j=wave; j<20; j+=8){
    const double* src=pnrhT+(size_t)j*PST;
    double s=0.0;
    for(int idx=lane; idx<NB; idx+=64) s+=src[idx];
    for(int off=32;off>0;off>>=1) s+=__shfl_down(s,off,64);
    if(lane==0) nrhd[j]=s;
  }
  __syncthreads();
  if(t<20){
    float nv=(float)(nrhd[t]/(bZ[0]+1e-16));
    in40[20+t]=nv; in40[t]=read_head[t];
    if(b==0) out[NRH_OFF+t]=nv;
  }
  if(b==0 && t==20){ Sd[0]=bZ[0]; Sd[1]=bZ[1]; }
  __syncthreads();
  // L1 redundant: 220 rows, K=40
  for(int r0=wave; r0<220; r0+=8){
    int net=(r0>=110), r=r0-net*110;
    const float* w=(net?mW1:aW1)+(size_t)r*40;
    float a=(lane<40)? w[lane]*in40[lane] : 0.f;
    for(int off=32;off>0;off>>=1) a+=__shfl_down(a,off,64);
    if(lane==0) h1s[r0]=fmaxf(a+(net?mb1:ab1)[r],0.f);
  }
  __syncthreads();
  // L2 redundant: 380 rows, K=110
#pragma unroll 2
  for(int r0=wave; r0<380; r0+=8){
    int net=(r0>=190), r=r0-net*190;
    const float* w=(net?mW2:aW2)+(size_t)r*110;
    const float* in=h1s+net*110;
    float a=0.f;
    for(int c=lane;c<110;c+=64) a+=w[c]*in[c];
    for(int off=32;off>0;off>>=1) a+=__shfl_down(a,off,64);
    if(lane==0) h2s[r0]=fmaxf(a+(net?mb2:ab2)[r],0.f);
  }
  __syncthreads();
  // L3 split: 540 rows over 64 blocks x 8 waves
  int wid=b*8+wave;
  for(int r0=wid; r0<540; r0+=512){
    int net=(r0>=270), r=r0-net*270;
    const float* w=(net?mW3:aW3)+(size_t)r*190;
    const float* in=h2s+net*190;
    float a=0.f;
    for(int c=lane;c<190;c+=64) a+=w[c]*in[c];
    for(int off=32;off>0;off>>=1) a+=__shfl_down(a,off,64);
    if(lane==0) h3g[r0]=fmaxf(a+(net?mb3:ab3)[r],0.f);
  }
}

// ------- K4: L4 split, one row per wave -------
__global__ __launch_bounds__(512) void k_mlpB(const float* __restrict__ h3g,
    const float* __restrict__ aW4,const float* __restrict__ ab4,
    const float* __restrict__ mW4,const float* __restrict__ mb4,
    float* __restrict__ h4g){
  int t=threadIdx.x, wave=t>>6, lane=t&63;
  int wid=blockIdx.x*8+wave;
  if(wid>=650) return;
  int net=(wid>=325), r=wid-net*325;
  const float* w=(net?mW4:aW4)+(size_t)r*270;
  const float* in=h3g+net*270;
  float a=0.f;
  for(int c=lane;c<270;c+=64) a+=w[c]*in[c];
  for(int off=32;off>0;off>>=1) a+=__shfl_down(a,off,64);
  if(lane==0) h4g[wid]=a+(net?mb4:ab4)[r];
}

// ------- K5: softmax both nets, combine, out, v, add_final -------
__global__ __launch_bounds__(512) void k_fin(const float* __restrict__ h4a, const float* __restrict__ h4m,
                      const float* __restrict__ Wv, const float* __restrict__ bv,
                      float* __restrict__ P, float* __restrict__ out){
  __shared__ float red[512];
  __shared__ float A[325], B[325];
  __shared__ float sc[2];
  int t=threadIdx.x;
  float la=(t<325)?h4a[t]:-3.0e38f;
  red[t]=la; __syncthreads();
  for(int o=256;o>0;o>>=1){ if(t<o) red[t]=fmaxf(red[t],red[t+o]); __syncthreads(); }
  if(t==0) sc[0]=red[0]; __syncthreads();
  float ea=(t<325)?expf(la-sc[0]):0.f;
  red[t]=ea; __syncthreads();
  for(int o=256;o>0;o>>=1){ if(t<o) red[t]+=red[t+o]; __syncthreads(); }
  if(t==0) sc[1]=red[0]; __syncthreads();
  if(t<325) A[t]=ea/sc[1];
  __syncthreads();
  float lm=(t<325)?h4m[t]:-3.0e38f;
  red[t]=lm; __syncthreads();
  for(int o=256;o>0;o>>=1){ if(t<o) red[t]=fmaxf(red[t],red[t+o]); __syncthreads(); }
  if(t==0) sc[0]=red[0]; __syncthreads();
  float em=(t<325)?expf(lm-sc[0]):0.f;
  red[t]=em; __syncthreads();
  for(int o=256;o>0;o>>=1){ if(t<o) red[t]+=red[t+o]; __syncthreads(); }
  if(t==0) sc[1]=red[0]; __syncthreads();
  if(t<325) B[t]=em/sc[1];
  __syncthreads();
  float ah0=P[105], ah1=P[106];
  if(t<325){ float ov=ah0*A[t]+ah1*B[t]; out[OUT_OFF+t]=ov; A[t]=ov; }
  __syncthreads();
  int wave=t>>6, lane=t&63;
  for(int r=wave; r<20; r+=8){
    const float* w=Wv+(size_t)r*325;
    float a=0.f;
    for(int c=lane;c<325;c+=64) a+=w[c]*A[c];
    for(int off=32;off>0;off>>=1) a+=__shfl_down(a,off,64);
    if(lane==0){
      float vv=a+bv[r];
      float rho=P[104];
      P[112+r]=rho*P[84+r]+(1.0f-rho)*vv;
    }
  }
}

// ------- K6: normalize rw/ww in place + new_memory (LDS-staged both directions) -------
__global__ __launch_bounds__(256) void k_memupd(const float* __restrict__ M,
                         float* __restrict__ w_r, float* __restrict__ w_w,
                         const float* __restrict__ P, const double* __restrict__ Sd,
                         float* __restrict__ nm){
  __shared__ float4 ld[1280];
  int t=threadIdx.x, b=blockIdx.x;
  float er[20], af[20];
#pragma unroll
  for(int j=0;j<20;j++){ er[j]=P[64+j]; af[j]=P[112+j]; }
  float Zr=(float)Sd[0]+1e-16f, Zw=(float)Sd[1]+1e-16f;
  const float4* Mf4=(const float4*)M;
  float4* nmf4=(float4*)nm;
  for(int p=0;p<4;p++){
    int rb=b*1024+p*256;
    size_t f4b=(size_t)rb*5;
#pragma unroll
    for(int k=0;k<5;k++){
      size_t idx=f4b+(size_t)(k*256+t);
      if(idx<NF4) ld[k*256+t]=Mf4[idx];
    }
    __syncthreads();
    int i=rb+t;
    if(i<NN){
      float wrn=w_r[i]/Zr;
      float wwn=w_w[i]/Zw;
      w_r[i]=wrn; w_w[i]=wwn;
#pragma unroll
      for(int q=0;q<5;q++){
        float4 v=ld[t*5+q];
        float4 o;
        o.x=v.x*(1.0f-wwn*er[4*q+0])+wwn*af[4*q+0];
        o.y=v.y*(1.0f-wwn*er[4*q+1])+wwn*af[4*q+1];
        o.z=v.z*(1.0f-wwn*er[4*q+2])+wwn*af[4*q+2];
        o.w=v.w*(1.0f-wwn*er[4*q+3])+wwn*af[4*q+3];
        ld[t*5+q]=o;
      }
    }
    __syncthreads();
#pragma unroll
    for(int k=0;k<5;k++){
      size_t idx=f4b+(size_t)(k*256+t);
      if(idx<NF4) nmf4[idx]=ld[k*256+t];
    }
    __syncthreads();
  }
}

extern "C" void kernel_launch(void* const* d_in, const int* in_sizes, int n_in,
                              void* d_out, int out_size, void* d_ws, size_t ws_size,
                              hipStream_t stream) {
  const float* X    =(const float*)d_in[0];
  const float* rwp  =(const float*)d_in[1];
  const float* wwp  =(const float*)d_in[2];
  const float* Mem  =(const float*)d_in[3];
  const float* rhd  =(const float*)d_in[4];
  const float* W1   =(const float*)d_in[5];
  const float* b1   =(const float*)d_in[6];
  const float* W2   =(const float*)d_in[7];
  const float* b2   =(const float*)d_in[8];
  const float* Wxi  =(const float*)d_in[9];
  const float* bxi  =(const float*)d_in[10];
  const float* Wz   =(const float*)d_in[11];
  const float* bz   =(const float*)d_in[12];
  const float* Wv   =(const float*)d_in[13];
  const float* bv   =(const float*)d_in[14];
  const float* aW1  =(const float*)d_in[15];
  const float* ab1  =(const float*)d_in[16];
  const float* aW2  =(const float*)d_in[17];
  const float* ab2  =(const float*)d_in[18];
  const float* aW3  =(const float*)d_in[19];
  const float* ab3  =(const float*)d_in[20];
  const float* aW4  =(const float*)d_in[21];
  const float* ab4  =(const float*)d_in[22];
  const float* mW1  =(const float*)d_in[23];
  const float* mb1  =(const float*)d_in[24];
  const float* mW2  =(const float*)d_in[25];
  const float* mb2  =(const float*)d_in[26];
  const float* mW3  =(const float*)d_in[27];
  const float* mb3  =(const float*)d_in[28];
  const float* mW4  =(const float*)d_in[29];
  const float* mb4  =(const float*)d_in[30];

  float* out = (float*)d_out;
  char* ws = (char*)d_ws;
  float*    P     = (float*)   (ws + 0);        // 256 floats
  double*   Sd    = (double*)  (ws + 2048);     // Z_r, Z_w
  float*    h3g   = (float*)   (ws + 4096);     // 540 floats
  float*    h4g   = (float*)   (ws + 8192);     // 650 floats
  float4*   pms   = (float4*)  (ws + 16384);    // NB float4
  double*   pZ    = (double*)  (ws + 32768);    // NB*2
  double*   pnrhT = (double*)  (ws + 65536);    // 20*PST (160 KB)

  float2* sc2 = (float2*)(out + NM_OFF);   // scores staged in dead nm region
  float*  w_r = out + RW_OFF;              // unnormalized until k_memupd
  float*  w_w = out + WW_OFF;
  float*  nm  = out + NM_OFF;

  k_scores<<<NB,256,0,stream>>>(X,W1,b1,W2,b2,Wxi,bxi,Wz,bz,Mem,P,sc2,pms);
  k_shift<<<NB,256,0,stream>>>(sc2,rwp,wwp,Mem,P,pms,w_r,w_w,pZ,pnrhT);
  k_mlpA<<<64,512,0,stream>>>(pZ,pnrhT,rhd,aW1,ab1,mW1,mb1,aW2,ab2,mW2,mb2,
                              aW3,ab3,mW3,mb3,out,Sd,h3g);
  k_mlpB<<<82,512,0,stream>>>(h3g,aW4,ab4,mW4,mb4,h4g);
  k_fin<<<1,512,0,stream>>>(h4g,h4g+325,Wv,bv,P,out);
  k_memupd<<<NB,256,0,stream>>>(Mem,w_r,w_w,P,Sd,nm);
}

// Round 6
// 176.741 us; speedup vs baseline: 1.0064x; 1.0064x over previous
//
#include <hip/hip_runtime.h>
#include <math.h>

#define NN 1000000
#define NF4 5000000       // NN*5 float4s in Memory
#define WD 20
#define NB 977            // blocks of 1024 rows
#define PST 1024          // pnrhT column stride

// d_out layout (floats): out[325] | rw[NN] | ww[NN] | new_memory[NN*20] | nrh[20]
#define OUT_OFF 0
#define RW_OFF  325
#define WW_OFF  1000325
#define NM_OFF  2000325
#define NRH_OFF 22000325

__device__ __forceinline__ float sigmoidf_(float x){ return 1.0f/(1.0f+expf(-x)); }
__device__ __forceinline__ float softplusf_(float x){ return (x>30.f)?x:log1pf(expf(x)); }

// ------- K1: controller-head prologue (redundant per block) + cosine scores -------
// P layout: kr:0-19 gr:20 sr:21-23 gammar:24 betar:25 knr:26
//           kw:32-51 gw:52 sw:53-55 gammaw:56 betaw:57 knw:58
//           erase:64-83 addraw:84-103 rho:104 ah0:105 ah1:106 addf:112-131
__global__ __launch_bounds__(256) void k_scores(
    const float* __restrict__ X,
    const float* __restrict__ W1, const float* __restrict__ b1,
    const float* __restrict__ W2, const float* __restrict__ b2,
    const float* __restrict__ Wxi, const float* __restrict__ bxi,
    const float* __restrict__ Wz, const float* __restrict__ bz,
    const float* __restrict__ M, float* __restrict__ Pg,
    float2* __restrict__ sc2, float4* __restrict__ pms){
  __shared__ float4 ld[1280];   // 20 KB
  __shared__ float h1[48], h2[72], xi[95], sP[132];
  int t=threadIdx.x, b=blockIdx.x;
  if(t<48){ float a=b1[t]; const float* w=W1+t*14; for(int c=0;c<14;c++) a+=X[c]*w[c]; h1[t]=a; }
  __syncthreads();
  if(t<72){ float a=b2[t]; const float* w=W2+t*48; for(int c=0;c<48;c++) a+=h1[c]*w[c]; h2[t]=a; }
  __syncthreads();
  if(t<92){ float a=bxi[t]; const float* w=Wxi+t*72; for(int c=0;c<72;c++) a+=h2[c]*w[c]; xi[t]=a; }
  else if(t<95){ int z=t-92; float a=bz[z]; const float* w=Wz+z*72; for(int c=0;c<72;c++) a+=h2[c]*w[c]; xi[92+z]=a; }
  __syncthreads();
  if(t<20){
    sP[0+t]  = tanhf(xi[t]);
    sP[32+t] = tanhf(xi[26+t]);
    sP[64+t] = sigmoidf_(xi[52+t]);
    sP[84+t] = tanhf(xi[72+t]);
  }
  __syncthreads();
  if(t==32){   // read-head scalars (wave 0)
    float g=sigmoidf_(xi[20]);
    float a0=xi[21],a1=xi[22],a2=xi[23];
    float mx=fmaxf(a0,fmaxf(a1,a2));
    float e0=expf(a0-mx),e1=expf(a1-mx),e2=expf(a2-mx),es=e0+e1+e2;
    float gamma=1.0f+softplusf_(xi[24]);
    float beta=softplusf_(xi[25]);
    float n2=0.f;
#pragma unroll
    for(int j=0;j<20;j++){ float ke=sP[j]+1e-16f; n2+=ke*ke; }
    sP[20]=g; sP[21]=e0/es; sP[22]=e1/es; sP[23]=e2/es; sP[24]=gamma; sP[25]=beta;
    sP[26]=fmaxf(sqrtf(n2),1e-8f);
  }
  if(t==96){   // write-head scalars (wave 1)
    float g=sigmoidf_(xi[46]);
    float a0=xi[47],a1=xi[48],a2=xi[49];
    float mx=fmaxf(a0,fmaxf(a1,a2));
    float e0=expf(a0-mx),e1=expf(a1-mx),e2=expf(a2-mx),es=e0+e1+e2;
    float gamma=1.0f+softplusf_(xi[50]);
    float beta=softplusf_(xi[51]);
    float n2=0.f;
#pragma unroll
    for(int j=0;j<20;j++){ float ke=sP[32+j]+1e-16f; n2+=ke*ke; }
    sP[52]=g; sP[53]=e0/es; sP[54]=e1/es; sP[55]=e2/es; sP[56]=gamma; sP[57]=beta;
    sP[58]=fmaxf(sqrtf(n2),1e-8f);
  }
  if(t==160){  // zeta scalars (wave 2)
    sP[104]=sigmoidf_(xi[92]);
    float mx=fmaxf(xi[93],xi[94]);
    float e1=expf(xi[93]-mx), e2=expf(xi[94]-mx);
    sP[105]=e1/(e1+e2); sP[106]=e2/(e1+e2);
  }
  __syncthreads();
  if(b==0 && t<132) Pg[t]=sP[t];
  float kr[20], kw[20];
#pragma unroll
  for(int j=0;j<20;j++){ kr[j]=sP[j]+1e-16f; kw[j]=sP[32+j]+1e-16f; }
  float betar=sP[25], betaw=sP[57], knr=sP[26], knw=sP[58];
  const float4* Mf4=(const float4*)M;
  float sR[4], sW[4];
  for(int p=0;p<4;p++){
    int rb=b*1024+p*256;
    size_t f4b=(size_t)rb*5;
#pragma unroll
    for(int k=0;k<5;k++){
      size_t idx=f4b+(size_t)(k*256+t);
      ld[k*256+t] = (idx<NF4)?Mf4[idx]:make_float4(0.f,0.f,0.f,0.f);
    }
    __syncthreads();
    int i=rb+t;
    float srv=-3.0e38f, swv=-3.0e38f;
    if(i<NN){
      float dr=0.f,dw=0.f,n2=0.f;
#pragma unroll
      for(int q=0;q<5;q++){
        float4 v=ld[t*5+q];
        float m0=v.x+1e-16f,m1=v.y+1e-16f,m2=v.z+1e-16f,m3=v.w+1e-16f;
        dr+=m0*kr[4*q]+m1*kr[4*q+1]+m2*kr[4*q+2]+m3*kr[4*q+3];
        dw+=m0*kw[4*q]+m1*kw[4*q+1]+m2*kw[4*q+2]+m3*kw[4*q+3];
        n2+=m0*m0+m1*m1+m2*m2+m3*m3;
      }
      float nm=fmaxf(sqrtf(n2),1e-8f);
      srv=betar*(dr/(nm*knr));
      swv=betaw*(dw/(nm*knw));
      sc2[i]=make_float2(srv,swv);
    }
    sR[p]=srv; sW[p]=swv;
    __syncthreads();
  }
  float* r1=(float*)ld; float* r2=r1+256;
  double* d1=(double*)(r1+512); double* d2=d1+256;
  float lm1=fmaxf(fmaxf(sR[0],sR[1]),fmaxf(sR[2],sR[3]));
  float lm2=fmaxf(fmaxf(sW[0],sW[1]),fmaxf(sW[2],sW[3]));
  r1[t]=lm1; r2[t]=lm2; __syncthreads();
  for(int o=128;o>0;o>>=1){ if(t<o){ r1[t]=fmaxf(r1[t],r1[t+o]); r2[t]=fmaxf(r2[t],r2[t+o]); } __syncthreads(); }
  float mb1=r1[0], mb2=r2[0]; __syncthreads();
  double s1=0.0,s2=0.0;
#pragma unroll
  for(int p=0;p<4;p++){ s1+=(double)expf(sR[p]-mb1); s2+=(double)expf(sW[p]-mb2); }
  d1[t]=s1; d2[t]=s2; __syncthreads();
  for(int o=128;o>0;o>>=1){ if(t<o){ d1[t]+=d1[t+o]; d2[t]+=d2[t+o]; } __syncthreads(); }
  if(t==0) pms[b]=make_float4(mb1,mb2,(float)d1[0],(float)d2[0]);
}

// ------- K2: interpolate+shift+pow; Z partials; fused rw@M (LDS-transposed) -------
__global__ __launch_bounds__(256) void k_shift(const float2* __restrict__ sc2,
                        const float* __restrict__ wpr, const float* __restrict__ wpw,
                        const float* __restrict__ M, const float* __restrict__ P,
                        const float4* __restrict__ pms,
                        float* __restrict__ w_r_out, float* __restrict__ w_w_out,
                        double* __restrict__ pZ, double* __restrict__ pnrhT){
  __shared__ float4 ld[1280];
  __shared__ float bmS[4];
  float* r1=(float*)ld; float* r2=r1+256;
  double* d1=(double*)(r1+512); double* d2=d1+256;
  float* wsum=(float*)(d2+256);  // [4][20]
  int t=threadIdx.x, b=blockIdx.x;
  float4 v4[4];
#pragma unroll
  for(int k=0;k<4;k++){
    int idx=t+k*256;
    v4[k] = (idx<NB) ? pms[idx] : make_float4(-3.0e38f,-3.0e38f,0.f,0.f);
  }
  float lm1=fmaxf(fmaxf(v4[0].x,v4[1].x),fmaxf(v4[2].x,v4[3].x));
  float lm2=fmaxf(fmaxf(v4[0].y,v4[1].y),fmaxf(v4[2].y,v4[3].y));
  r1[t]=lm1; r2[t]=lm2; __syncthreads();
  for(int o=128;o>0;o>>=1){ if(t<o){ r1[t]=fmaxf(r1[t],r1[t+o]); r2[t]=fmaxf(r2[t],r2[t+o]); } __syncthreads(); }
  if(t==0){ bmS[0]=r1[0]; bmS[1]=r2[0]; } __syncthreads();
  float mr=bmS[0], mw=bmS[1];
  double s1=0.0,s2=0.0;
#pragma unroll
  for(int k=0;k<4;k++){
    s1 += (double)v4[k].z * (double)expf(v4[k].x-mr);
    s2 += (double)v4[k].w * (double)expf(v4[k].y-mw);
  }
  d1[t]=s1; d2[t]=s2; __syncthreads();
  for(int o=128;o>0;o>>=1){ if(t<o){ d1[t]+=d1[t+o]; d2[t]+=d2[t+o]; } __syncthreads(); }
  if(t==0){ bmS[2]=(float)d1[0]; bmS[3]=(float)d2[0]; } __syncthreads();
  float Sr=bmS[2], Sw=bmS[3];
  float gr=P[20], s0r=P[21], s1r=P[22], s2r=P[23], gar=P[24];
  float gw=P[52], s0w=P[53], s1w=P[54], s2w=P[55], gaw=P[56];
  float omgr=1.0f-gr, omgw=1.0f-gw;
  const float4* Mf4=(const float4*)M;
  float acc[20];
#pragma unroll
  for(int j=0;j<20;j++) acc[j]=0.f;
  double zr=0.0, zw=0.0;
  for(int p=0;p<4;p++){
    int rb=b*1024+p*256;
    size_t f4b=(size_t)rb*5;
#pragma unroll
    for(int k=0;k<5;k++){
      size_t idx=f4b+(size_t)(k*256+t);
      ld[k*256+t] = (idx<NF4)?Mf4[idx]:make_float4(0.f,0.f,0.f,0.f);
    }
    __syncthreads();
    int i=rb+t;
    if(i<NN){
      int im1=(i==0)?(NN-1):(i-1);
      int ip1=(i==NN-1)?0:(i+1);
      float2 scm=sc2[im1], sc0=sc2[i], scp=sc2[ip1];
      float wgrm = gr*(expf(scm.x-mr)/Sr) + omgr*wpr[im1];
      float wgr0 = gr*(expf(sc0.x-mr)/Sr) + omgr*wpr[i  ];
      float wgrp = gr*(expf(scp.x-mr)/Sr) + omgr*wpr[ip1];
      float wgwm = gw*(expf(scm.y-mw)/Sw) + omgw*wpw[im1];
      float wgw0 = gw*(expf(sc0.y-mw)/Sw) + omgw*wpw[i  ];
      float wgwp = gw*(expf(scp.y-mw)/Sw) + omgw*wpw[ip1];
      float wr = powf(s0r*wgrm + s1r*wgr0 + s2r*wgrp, gar);
      float ww = powf(s0w*wgwm + s1w*wgw0 + s2w*wgwp, gaw);
      w_r_out[i]=wr; w_w_out[i]=ww;
      zr+=(double)wr; zw+=(double)ww;
#pragma unroll
      for(int q=0;q<5;q++){
        float4 mv=ld[t*5+q];
        acc[4*q+0]+=wr*mv.x; acc[4*q+1]+=wr*mv.y; acc[4*q+2]+=wr*mv.z; acc[4*q+3]+=wr*mv.w;
      }
    }
    __syncthreads();
  }
  d1[t]=zr; d2[t]=zw; __syncthreads();
  for(int o=128;o>0;o>>=1){ if(t<o){ d1[t]+=d1[t+o]; d2[t]+=d2[t+o]; } __syncthreads(); }
  if(t==0){ pZ[2*b]=d1[0]; pZ[2*b+1]=d2[0]; }
  __syncthreads();
#pragma unroll
  for(int j=0;j<20;j++){
    for(int off=32;off>0;off>>=1) acc[j]+=__shfl_down(acc[j],off,64);
  }
  int wave=t>>6, lane=t&63;
  if(lane==0){
#pragma unroll
    for(int j=0;j<20;j++) wsum[wave*20+j]=acc[j];
  }
  __syncthreads();
  if(t<20){
    double s=(double)wsum[0*20+t]+(double)wsum[1*20+t]+(double)wsum[2*20+t]+(double)wsum[3*20+t];
    pnrhT[(size_t)t*PST+b]=s;
  }
}

// ------- K3: single-block full MLP tail (reduces + 4 layers + softmax + v) -------
__global__ __launch_bounds__(1024) void k_tail(
    const double* __restrict__ pZ, const double* __restrict__ pnrhT,
    const float* __restrict__ read_head,
    const float* __restrict__ aW1,const float* __restrict__ ab1,
    const float* __restrict__ aW2,const float* __restrict__ ab2,
    const float* __restrict__ aW3,const float* __restrict__ ab3,
    const float* __restrict__ aW4,const float* __restrict__ ab4,
    const float* __restrict__ mW1,const float* __restrict__ mb1,
    const float* __restrict__ mW2,const float* __restrict__ mb2,
    const float* __restrict__ mW3,const float* __restrict__ mb3,
    const float* __restrict__ mW4,const float* __restrict__ mb4,
    const float* __restrict__ Wv, const float* __restrict__ bv,
    float* __restrict__ P, float* __restrict__ out, double* __restrict__ Sd){
  __shared__ float in40[40], h1s[220], h2s[380], h3s[540], h4s[650];
  __shared__ float probA[325], probB[325], outv[325];
  __shared__ float red[1024];
  __shared__ double nrhd[20], bZ[2];
  int t=threadIdx.x, wave=t>>6, lane=t&63;
  // --- prefetch all weights (coalesced stream into L2; dummy-consumed at end) ---
  float pref=0.f;
  {
    const float4* a4;
    a4=(const float4*)aW1; for(int i=t;i<1100;i+=1024)  pref+=a4[i].x;
    a4=(const float4*)mW1; for(int i=t;i<1100;i+=1024)  pref+=a4[i].x;
    a4=(const float4*)aW2; for(int i=t;i<5225;i+=1024)  pref+=a4[i].x;
    a4=(const float4*)mW2; for(int i=t;i<5225;i+=1024)  pref+=a4[i].x;
    a4=(const float4*)aW3; for(int i=t;i<12825;i+=1024) pref+=a4[i].x;
    a4=(const float4*)mW3; for(int i=t;i<12825;i+=1024) pref+=a4[i].x;
    a4=(const float4*)aW4; for(int i=t;i<21937;i+=1024) pref+=a4[i].x;
    a4=(const float4*)mW4; for(int i=t;i<21937;i+=1024) pref+=a4[i].x;
  }
  // --- Z reduces (waves 0,1) + nrh column reduces (all waves) ---
  if(wave<2){
    double s=0.0;
    for(int idx=lane; idx<NB; idx+=64) s+=pZ[2*idx+wave];
    for(int off=32;off>0;off>>=1) s+=__shfl_down(s,off,64);
    if(lane==0) bZ[wave]=s;
  }
  for(int j=wave; j<20; j+=16){
    const double* src=pnrhT+(size_t)j*PST;
    double s=0.0;
    for(int idx=lane; idx<NB; idx+=64) s+=src[idx];
    for(int off=32;off>0;off>>=1) s+=__shfl_down(s,off,64);
    if(lane==0) nrhd[j]=s;
  }
  __syncthreads();
  if(t<20){
    float nv=(float)(nrhd[t]/(bZ[0]+1e-16));
    in40[20+t]=nv; in40[t]=read_head[t];
    out[NRH_OFF+t]=nv;
  }
  if(t==20){ Sd[0]=bZ[0]; Sd[1]=bZ[1]; }
  __syncthreads();
  int g=t>>4, l16=t&15;   // 64 groups of 16 lanes
  // L1: 220 rows, K=40
  for(int pass=0; pass<4; ++pass){
    int r0=pass*64+g;
    if(r0<220){
      int net=(r0>=110), r=r0-net*110;
      const float* w=(net?mW1:aW1)+(size_t)r*40;
      float a=0.f;
      for(int c=l16;c<40;c+=16) a+=w[c]*in40[c];
      a+=__shfl_xor(a,8,64); a+=__shfl_xor(a,4,64); a+=__shfl_xor(a,2,64); a+=__shfl_xor(a,1,64);
      if(l16==0) h1s[r0]=fmaxf(a+(net?mb1:ab1)[r],0.f);
    }
  }
  __syncthreads();
  // L2: 380 rows, K=110
  for(int pass=0; pass<6; ++pass){
    int r0=pass*64+g;
    if(r0<380){
      int net=(r0>=190), r=r0-net*190;
      const float* w=(net?mW2:aW2)+(size_t)r*110;
      const float* in=h1s+net*110;
      float a=0.f;
      for(int c=l16;c<110;c+=16) a+=w[c]*in[c];
      a+=__shfl_xor(a,8,64); a+=__shfl_xor(a,4,64); a+=__shfl_xor(a,2,64); a+=__shfl_xor(a,1,64);
      if(l16==0) h2s[r0]=fmaxf(a+(net?mb2:ab2)[r],0.f);
    }
  }
  __syncthreads();
  // L3: 540 rows, K=190
  for(int pass=0; pass<9; ++pass){
    int r0=pass*64+g;
    if(r0<540){
      int net=(r0>=270), r=r0-net*270;
      const float* w=(net?mW3:aW3)+(size_t)r*190;
      const float* in=h2s+net*190;
      float a=0.f;
      for(int c=l16;c<190;c+=16) a+=w[c]*in[c];
      a+=__shfl_xor(a,8,64); a+=__shfl_xor(a,4,64); a+=__shfl_xor(a,2,64); a+=__shfl_xor(a,1,64);
      if(l16==0) h3s[r0]=fmaxf(a+(net?mb3:ab3)[r],0.f);
    }
  }
  __syncthreads();
  // L4: 650 rows, K=270, no relu
  for(int pass=0; pass<11; ++pass){
    int r0=pass*64+g;
    if(r0<650){
      int net=(r0>=325), r=r0-net*325;
      const float* w=(net?mW4:aW4)+(size_t)r*270;
      const float* in=h3s+net*270;
      float a=0.f;
      for(int c=l16;c<270;c+=16) a+=w[c]*in[c];
      a+=__shfl_xor(a,8,64); a+=__shfl_xor(a,4,64); a+=__shfl_xor(a,2,64); a+=__shfl_xor(a,1,64);
      if(l16==0) h4s[r0]=a+(net?mb4:ab4)[r];
    }
  }
  __syncthreads();
  // dual softmax: threads [0,512) -> net A, [512,1024) -> net M
  int half=t>>9, li=t&511, base=half<<9;
  float v=(li<325)? h4s[half*325+li] : -3.0e38f;
  red[t]=v; __syncthreads();
  for(int o=256;o>0;o>>=1){ if(li<o) red[base+li]=fmaxf(red[base+li],red[base+li+o]); __syncthreads(); }
  float mx=red[base]; __syncthreads();
  float e=(li<325)? expf(v-mx):0.f;
  red[t]=e; __syncthreads();
  for(int o=256;o>0;o>>=1){ if(li<o) red[base+li]+=red[base+li+o]; __syncthreads(); }
  float sum=red[base]; __syncthreads();
  if(li<325){ if(half==0) probA[li]=e/sum; else probB[li]=e/sum; }
  __syncthreads();
  float ah0=P[105], ah1=P[106];
  if(t<325){ float ov=ah0*probA[t]+ah1*probB[t]; outv[t]=ov; out[OUT_OFF+t]=ov; }
  __syncthreads();
  // v = Wv @ outv + bv; add_final -> P[112..131]
  for(int r=wave; r<20; r+=16){
    const float* w=Wv+(size_t)r*325;
    float a=0.f;
    for(int c=lane;c<325;c+=64) a+=w[c]*outv[c];
    for(int off=32;off>0;off>>=1) a+=__shfl_down(a,off,64);
    if(lane==0){
      float vv=a+bv[r];
      float rho=P[104];
      P[112+r]=rho*P[84+r]+(1.0f-rho)*vv;
    }
  }
  if(pref==1.2345e37f) Sd[3]=(double)pref;   // keep prefetch loads live (never true)
}

// ------- K4: normalize rw/ww in place + new_memory (LDS-staged both directions) -------
__global__ __launch_bounds__(256) void k_memupd(const float* __restrict__ M,
                         float* __restrict__ w_r, float* __restrict__ w_w,
                         const float* __restrict__ P, const double* __restrict__ Sd,
                         float* __restrict__ nm){
  __shared__ float4 ld[1280];
  int t=threadIdx.x, b=blockIdx.x;
  float er[20], af[20];
#pragma unroll
  for(int j=0;j<20;j++){ er[j]=P[64+j]; af[j]=P[112+j]; }
  float Zr=(float)Sd[0]+1e-16f, Zw=(float)Sd[1]+1e-16f;
  const float4* Mf4=(const float4*)M;
  float4* nmf4=(float4*)nm;
  for(int p=0;p<4;p++){
    int rb=b*1024+p*256;
    size_t f4b=(size_t)rb*5;
#pragma unroll
    for(int k=0;k<5;k++){
      size_t idx=f4b+(size_t)(k*256+t);
      if(idx<NF4) ld[k*256+t]=Mf4[idx];
    }
    __syncthreads();
    int i=rb+t;
    if(i<NN){
      float wrn=w_r[i]/Zr;
      float wwn=w_w[i]/Zw;
      w_r[i]=wrn; w_w[i]=wwn;
#pragma unroll
      for(int q=0;q<5;q++){
        float4 v=ld[t*5+q];
        float4 o;
        o.x=v.x*(1.0f-wwn*er[4*q+0])+wwn*af[4*q+0];
        o.y=v.y*(1.0f-wwn*er[4*q+1])+wwn*af[4*q+1];
        o.z=v.z*(1.0f-wwn*er[4*q+2])+wwn*af[4*q+2];
        o.w=v.w*(1.0f-wwn*er[4*q+3])+wwn*af[4*q+3];
        ld[t*5+q]=o;
      }
    }
    __syncthreads();
#pragma unroll
    for(int k=0;k<5;k++){
      size_t idx=f4b+(size_t)(k*256+t);
      if(idx<NF4) nmf4[idx]=ld[k*256+t];
    }
    __syncthreads();
  }
}

extern "C" void kernel_launch(void* const* d_in, const int* in_sizes, int n_in,
                              void* d_out, int out_size, void* d_ws, size_t ws_size,
                              hipStream_t stream) {
  const float* X    =(const float*)d_in[0];
  const float* rwp  =(const float*)d_in[1];
  const float* wwp  =(const float*)d_in[2];
  const float* Mem  =(const float*)d_in[3];
  const float* rhd  =(const float*)d_in[4];
  const float* W1   =(const float*)d_in[5];
  const float* b1   =(const float*)d_in[6];
  const float* W2   =(const float*)d_in[7];
  const float* b2   =(const float*)d_in[8];
  const float* Wxi  =(const float*)d_in[9];
  const float* bxi  =(const float*)d_in[10];
  const float* Wz   =(const float*)d_in[11];
  const float* bz   =(const float*)d_in[12];
  const float* Wv   =(const float*)d_in[13];
  const float* bv   =(const float*)d_in[14];
  const float* aW1  =(const float*)d_in[15];
  const float* ab1  =(const float*)d_in[16];
  const float* aW2  =(const float*)d_in[17];
  const float* ab2  =(const float*)d_in[18];
  const float* aW3  =(const float*)d_in[19];
  const float* ab3  =(const float*)d_in[20];
  const float* aW4  =(const float*)d_in[21];
  const float* ab4  =(const float*)d_in[22];
  const float* mW1  =(const float*)d_in[23];
  const float* mb1  =(const float*)d_in[24];
  const float* mW2  =(const float*)d_in[25];
  const float* mb2  =(const float*)d_in[26];
  const float* mW3  =(const float*)d_in[27];
  const float* mb3  =(const float*)d_in[28];
  const float* mW4  =(const float*)d_in[29];
  const float* mb4  =(const float*)d_in[30];

  float* out = (float*)d_out;
  char* ws = (char*)d_ws;
  float*    P     = (float*)   (ws + 0);        // 256 floats
  double*   Sd    = (double*)  (ws + 2048);     // Z_r, Z_w, spare
  float4*   pms   = (float4*)  (ws + 16384);    // NB float4
  double*   pZ    = (double*)  (ws + 32768);    // NB*2
  double*   pnrhT = (double*)  (ws + 65536);    // 20*PST (160 KB)

  float2* sc2 = (float2*)(out + NM_OFF);   // scores staged in dead nm region
  float*  w_r = out + RW_OFF;              // unnormalized until k_memupd
  float*  w_w = out + WW_OFF;
  float*  nm  = out + NM_OFF;

  k_scores<<<NB,256,0,stream>>>(X,W1,b1,W2,b2,Wxi,bxi,Wz,bz,Mem,P,sc2,pms);
  k_shift<<<NB,256,0,stream>>>(sc2,rwp,wwp,Mem,P,pms,w_r,w_w,pZ,pnrhT);
  k_tail<<<1,1024,0,stream>>>(pZ,pnrhT,rhd,
                              aW1,ab1,aW2,ab2,aW3,ab3,aW4,ab4,
                              mW1,mb1,mW2,mb2,mW3,mb3,mW4,mb4,
                              Wv,bv,P,out,Sd);
  k_memupd<<<NB,256,0,stream>>>(Mem,w_r,w_w,P,Sd,nm);
}

// Round 7
// 139.603 us; speedup vs baseline: 1.2741x; 1.2660x over previous
//
#include <hip/hip_runtime.h>
#include <math.h>

#define NN 1000000
#define NF4 5000000       // NN*5 float4s in Memory
#define WD 20
#define NB 977            // blocks of 1024 rows
#define FXS 4.398046511104e12   // 2^42 fixed-point scale for deterministic atomics

// d_out layout (floats): out[325] | rw[NN] | ww[NN] | new_memory[NN*20] | nrh[20]
#define OUT_OFF 0
#define RW_OFF  325
#define WW_OFF  1000325
#define NM_OFF  2000325
#define NRH_OFF 22000325

typedef unsigned long long ull;

__device__ __forceinline__ float sigmoidf_(float x){ return 1.0f/(1.0f+expf(-x)); }
__device__ __forceinline__ float softplusf_(float x){ return (x>30.f)?x:log1pf(expf(x)); }
__device__ __forceinline__ double decfx(ull v){ return (double)(long long)v * (1.0/FXS); }
__device__ __forceinline__ void accfx(ull* p, double s){
  long long q=(long long)llrint(s*FXS);
  atomicAdd(p,(ull)q);
}

// ------- K1: controller-head prologue (redundant per block) + cosine scores -------
// P layout: kr:0-19 gr:20 sr:21-23 gammar:24 betar:25 knr:26
//           kw:32-51 gw:52 sw:53-55 gammaw:56 betaw:57 knw:58
//           erase:64-83 addraw:84-103 rho:104 ah0:105 ah1:106
// acc layout (ull, fixed-point 2^42): 0-19 nrh sums | 20 Z_r | 21 Z_w
__global__ __launch_bounds__(256) void k_scores(
    const float* __restrict__ X,
    const float* __restrict__ W1, const float* __restrict__ b1,
    const float* __restrict__ W2, const float* __restrict__ b2,
    const float* __restrict__ Wxi, const float* __restrict__ bxi,
    const float* __restrict__ Wz, const float* __restrict__ bz,
    const float* __restrict__ M, float* __restrict__ Pg, ull* __restrict__ acc,
    float2* __restrict__ sc2, float4* __restrict__ pms){
  __shared__ float4 ld[1280];   // 20 KB
  __shared__ float h1[48], h2[72], xi[95], sP[132];
  int t=threadIdx.x, b=blockIdx.x;
  if(b==0 && t<24) acc[t]=0ull;          // zero accumulators each call
  if(t<48){ float a=b1[t]; const float* w=W1+t*14; for(int c=0;c<14;c++) a+=X[c]*w[c]; h1[t]=a; }
  __syncthreads();
  if(t<72){ float a=b2[t]; const float* w=W2+t*48; for(int c=0;c<48;c++) a+=h1[c]*w[c]; h2[t]=a; }
  __syncthreads();
  if(t<92){ float a=bxi[t]; const float* w=Wxi+t*72; for(int c=0;c<72;c++) a+=h2[c]*w[c]; xi[t]=a; }
  else if(t<95){ int z=t-92; float a=bz[z]; const float* w=Wz+z*72; for(int c=0;c<72;c++) a+=h2[c]*w[c]; xi[92+z]=a; }
  __syncthreads();
  if(t<20){
    sP[0+t]  = tanhf(xi[t]);
    sP[32+t] = tanhf(xi[26+t]);
    sP[64+t] = sigmoidf_(xi[52+t]);
    sP[84+t] = tanhf(xi[72+t]);
  }
  __syncthreads();
  if(t==32){   // read-head scalars (wave 0)
    float g=sigmoidf_(xi[20]);
    float a0=xi[21],a1=xi[22],a2=xi[23];
    float mx=fmaxf(a0,fmaxf(a1,a2));
    float e0=expf(a0-mx),e1=expf(a1-mx),e2=expf(a2-mx),es=e0+e1+e2;
    float gamma=1.0f+softplusf_(xi[24]);
    float beta=softplusf_(xi[25]);
    float n2=0.f;
#pragma unroll
    for(int j=0;j<20;j++){ float ke=sP[j]+1e-16f; n2+=ke*ke; }
    sP[20]=g; sP[21]=e0/es; sP[22]=e1/es; sP[23]=e2/es; sP[24]=gamma; sP[25]=beta;
    sP[26]=fmaxf(sqrtf(n2),1e-8f);
  }
  if(t==96){   // write-head scalars (wave 1)
    float g=sigmoidf_(xi[46]);
    float a0=xi[47],a1=xi[48],a2=xi[49];
    float mx=fmaxf(a0,fmaxf(a1,a2));
    float e0=expf(a0-mx),e1=expf(a1-mx),e2=expf(a2-mx),es=e0+e1+e2;
    float gamma=1.0f+softplusf_(xi[50]);
    float beta=softplusf_(xi[51]);
    float n2=0.f;
#pragma unroll
    for(int j=0;j<20;j++){ float ke=sP[32+j]+1e-16f; n2+=ke*ke; }
    sP[52]=g; sP[53]=e0/es; sP[54]=e1/es; sP[55]=e2/es; sP[56]=gamma; sP[57]=beta;
    sP[58]=fmaxf(sqrtf(n2),1e-8f);
  }
  if(t==160){  // zeta scalars (wave 2)
    sP[104]=sigmoidf_(xi[92]);
    float mx=fmaxf(xi[93],xi[94]);
    float e1=expf(xi[93]-mx), e2=expf(xi[94]-mx);
    sP[105]=e1/(e1+e2); sP[106]=e2/(e1+e2);
  }
  __syncthreads();
  if(b==0 && t<132) Pg[t]=sP[t];
  float kr[20], kw[20];
#pragma unroll
  for(int j=0;j<20;j++){ kr[j]=sP[j]+1e-16f; kw[j]=sP[32+j]+1e-16f; }
  float betar=sP[25], betaw=sP[57], knr=sP[26], knw=sP[58];
  const float4* Mf4=(const float4*)M;
  float sR[4], sW[4];
  for(int p=0;p<4;p++){
    int rb=b*1024+p*256;
    size_t f4b=(size_t)rb*5;
#pragma unroll
    for(int k=0;k<5;k++){
      size_t idx=f4b+(size_t)(k*256+t);
      ld[k*256+t] = (idx<NF4)?Mf4[idx]:make_float4(0.f,0.f,0.f,0.f);
    }
    __syncthreads();
    int i=rb+t;
    float srv=-3.0e38f, swv=-3.0e38f;
    if(i<NN){
      float dr=0.f,dw=0.f,n2=0.f;
#pragma unroll
      for(int q=0;q<5;q++){
        float4 v=ld[t*5+q];
        float m0=v.x+1e-16f,m1=v.y+1e-16f,m2=v.z+1e-16f,m3=v.w+1e-16f;
        dr+=m0*kr[4*q]+m1*kr[4*q+1]+m2*kr[4*q+2]+m3*kr[4*q+3];
        dw+=m0*kw[4*q]+m1*kw[4*q+1]+m2*kw[4*q+2]+m3*kw[4*q+3];
        n2+=m0*m0+m1*m1+m2*m2+m3*m3;
      }
      float nm=fmaxf(sqrtf(n2),1e-8f);
      srv=betar*(dr/(nm*knr));
      swv=betaw*(dw/(nm*knw));
      sc2[i]=make_float2(srv,swv);
    }
    sR[p]=srv; sW[p]=swv;
    __syncthreads();
  }
  float* r1=(float*)ld; float* r2=r1+256;
  double* d1=(double*)(r1+512); double* d2=d1+256;
  float lm1=fmaxf(fmaxf(sR[0],sR[1]),fmaxf(sR[2],sR[3]));
  float lm2=fmaxf(fmaxf(sW[0],sW[1]),fmaxf(sW[2],sW[3]));
  r1[t]=lm1; r2[t]=lm2; __syncthreads();
  for(int o=128;o>0;o>>=1){ if(t<o){ r1[t]=fmaxf(r1[t],r1[t+o]); r2[t]=fmaxf(r2[t],r2[t+o]); } __syncthreads(); }
  float mb1=r1[0], mb2=r2[0]; __syncthreads();
  double s1=0.0,s2=0.0;
#pragma unroll
  for(int p=0;p<4;p++){ s1+=(double)expf(sR[p]-mb1); s2+=(double)expf(sW[p]-mb2); }
  d1[t]=s1; d2[t]=s2; __syncthreads();
  for(int o=128;o>0;o>>=1){ if(t<o){ d1[t]+=d1[t+o]; d2[t]+=d2[t+o]; } __syncthreads(); }
  if(t==0) pms[b]=make_float4(mb1,mb2,(float)d1[0],(float)d2[0]);
}

// ------- K2: interpolate+shift+pow; fused rw@M; fixed-point atomic accumulation -------
__global__ __launch_bounds__(256) void k_shift(const float2* __restrict__ sc2,
                        const float* __restrict__ wpr, const float* __restrict__ wpw,
                        const float* __restrict__ M, const float* __restrict__ P,
                        const float4* __restrict__ pms,
                        float* __restrict__ w_r_out, float* __restrict__ w_w_out,
                        ull* __restrict__ acc_g){
  __shared__ float4 ld[1280];
  __shared__ float bmS[4];
  float* r1=(float*)ld; float* r2=r1+256;
  double* d1=(double*)(r1+512); double* d2=d1+256;
  float* wsum=(float*)(d2+256);  // [4][20]
  int t=threadIdx.x, b=blockIdx.x;
  float4 v4[4];
#pragma unroll
  for(int k=0;k<4;k++){
    int idx=t+k*256;
    v4[k] = (idx<NB) ? pms[idx] : make_float4(-3.0e38f,-3.0e38f,0.f,0.f);
  }
  float lm1=fmaxf(fmaxf(v4[0].x,v4[1].x),fmaxf(v4[2].x,v4[3].x));
  float lm2=fmaxf(fmaxf(v4[0].y,v4[1].y),fmaxf(v4[2].y,v4[3].y));
  r1[t]=lm1; r2[t]=lm2; __syncthreads();
  for(int o=128;o>0;o>>=1){ if(t<o){ r1[t]=fmaxf(r1[t],r1[t+o]); r2[t]=fmaxf(r2[t],r2[t+o]); } __syncthreads(); }
  if(t==0){ bmS[0]=r1[0]; bmS[1]=r2[0]; } __syncthreads();
  float mr=bmS[0], mw=bmS[1];
  double s1=0.0,s2=0.0;
#pragma unroll
  for(int k=0;k<4;k++){
    s1 += (double)v4[k].z * (double)expf(v4[k].x-mr);
    s2 += (double)v4[k].w * (double)expf(v4[k].y-mw);
  }
  d1[t]=s1; d2[t]=s2; __syncthreads();
  for(int o=128;o>0;o>>=1){ if(t<o){ d1[t]+=d1[t+o]; d2[t]+=d2[t+o]; } __syncthreads(); }
  if(t==0){ bmS[2]=(float)d1[0]; bmS[3]=(float)d2[0]; } __syncthreads();
  float Sr=bmS[2], Sw=bmS[3];
  float gr=P[20], s0r=P[21], s1r=P[22], s2r=P[23], gar=P[24];
  float gw=P[52], s0w=P[53], s1w=P[54], s2w=P[55], gaw=P[56];
  float omgr=1.0f-gr, omgw=1.0f-gw;
  const float4* Mf4=(const float4*)M;
  float acc[20];
#pragma unroll
  for(int j=0;j<20;j++) acc[j]=0.f;
  double zr=0.0, zw=0.0;
  for(int p=0;p<4;p++){
    int rb=b*1024+p*256;
    size_t f4b=(size_t)rb*5;
#pragma unroll
    for(int k=0;k<5;k++){
      size_t idx=f4b+(size_t)(k*256+t);
      ld[k*256+t] = (idx<NF4)?Mf4[idx]:make_float4(0.f,0.f,0.f,0.f);
    }
    __syncthreads();
    int i=rb+t;
    if(i<NN){
      int im1=(i==0)?(NN-1):(i-1);
      int ip1=(i==NN-1)?0:(i+1);
      float2 scm=sc2[im1], sc0=sc2[i], scp=sc2[ip1];
      float wgrm = gr*(expf(scm.x-mr)/Sr) + omgr*wpr[im1];
      float wgr0 = gr*(expf(sc0.x-mr)/Sr) + omgr*wpr[i  ];
      float wgrp = gr*(expf(scp.x-mr)/Sr) + omgr*wpr[ip1];
      float wgwm = gw*(expf(scm.y-mw)/Sw) + omgw*wpw[im1];
      float wgw0 = gw*(expf(sc0.y-mw)/Sw) + omgw*wpw[i  ];
      float wgwp = gw*(expf(scp.y-mw)/Sw) + omgw*wpw[ip1];
      float wr = powf(s0r*wgrm + s1r*wgr0 + s2r*wgrp, gar);
      float ww = powf(s0w*wgwm + s1w*wgw0 + s2w*wgwp, gaw);
      w_r_out[i]=wr; w_w_out[i]=ww;
      zr+=(double)wr; zw+=(double)ww;
#pragma unroll
      for(int q=0;q<5;q++){
        float4 mv=ld[t*5+q];
        acc[4*q+0]+=wr*mv.x; acc[4*q+1]+=wr*mv.y; acc[4*q+2]+=wr*mv.z; acc[4*q+3]+=wr*mv.w;
      }
    }
    __syncthreads();
  }
  d1[t]=zr; d2[t]=zw; __syncthreads();
  for(int o=128;o>0;o>>=1){ if(t<o){ d1[t]+=d1[t+o]; d2[t]+=d2[t+o]; } __syncthreads(); }
  if(t==0){ accfx(acc_g+20,d1[0]); accfx(acc_g+21,d2[0]); }
  __syncthreads();
#pragma unroll
  for(int j=0;j<20;j++){
    for(int off=32;off>0;off>>=1) acc[j]+=__shfl_down(acc[j],off,64);
  }
  int wave=t>>6, lane=t&63;
  if(lane==0){
#pragma unroll
    for(int j=0;j<20;j++) wsum[wave*20+j]=acc[j];
  }
  __syncthreads();
  if(t<20){
    double s=(double)wsum[0*20+t]+(double)wsum[1*20+t]+(double)wsum[2*20+t]+(double)wsum[3*20+t];
    accfx(acc_g+t,s);
  }
}

// ------- K3: in40 + redundant L1 (own net) + distributed L2 -------
__global__ __launch_bounds__(256) void k_l12(const ull* __restrict__ acc,
    const float* __restrict__ read_head,
    const float* __restrict__ aW1,const float* __restrict__ ab1,
    const float* __restrict__ mW1,const float* __restrict__ mb1,
    const float* __restrict__ aW2,const float* __restrict__ ab2,
    const float* __restrict__ mW2,const float* __restrict__ mb2,
    float* __restrict__ out, float* __restrict__ h2g){
  __shared__ float in40[40], h1s[110];
  int t=threadIdx.x, b=blockIdx.x;
  int net=(b>=48);
  if(t<20){
    double Zr=decfx(acc[20])+1e-16;
    float nv=(float)(decfx(acc[t])/Zr);
    in40[20+t]=nv; in40[t]=read_head[t];
    if(b==0) out[NRH_OFF+t]=nv;
  }
  __syncthreads();
  int g=t>>4, l16=t&15;
  const float* W1=net?mW1:aW1; const float* B1=net?mb1:ab1;
  for(int pass=0; pass<7; ++pass){
    int r=pass*16+g;
    if(r<110){
      const float* w=W1+(size_t)r*40;
      float a=0.f;
      for(int c=l16;c<40;c+=16) a+=w[c]*in40[c];
      a+=__shfl_xor(a,8,64); a+=__shfl_xor(a,4,64); a+=__shfl_xor(a,2,64); a+=__shfl_xor(a,1,64);
      if(l16==0) h1s[r]=fmaxf(a+B1[r],0.f);
    }
  }
  __syncthreads();
  int wave=t>>6, lane=t&63;
  int r=(b-net*48)*4+wave;
  if(r<190){
    const float* w=(net?mW2:aW2)+(size_t)r*110;
    float a=0.f;
    for(int c=lane;c<110;c+=64) a+=w[c]*h1s[c];
    for(int off=32;off>0;off>>=1) a+=__shfl_down(a,off,64);
    if(lane==0) h2g[net*190+r]=fmaxf(a+(net?mb2:ab2)[r],0.f);
  }
}

// ------- K4: L3 distributed -------
__global__ __launch_bounds__(256) void k_l3(const float* __restrict__ h2g,
    const float* __restrict__ aW3,const float* __restrict__ ab3,
    const float* __restrict__ mW3,const float* __restrict__ mb3,
    float* __restrict__ h3g){
  int t=threadIdx.x, b=blockIdx.x, wave=t>>6, lane=t&63;
  int net=(b>=68);
  int r=(b-net*68)*4+wave;
  if(r>=270) return;
  const float* w=(net?mW3:aW3)+(size_t)r*190;
  const float* in=h2g+net*190;
  float a=0.f;
  for(int c=lane;c<190;c+=64) a+=w[c]*in[c];
  for(int off=32;off>0;off>>=1) a+=__shfl_down(a,off,64);
  if(lane==0) h3g[net*270+r]=fmaxf(a+(net?mb3:ab3)[r],0.f);
}

// ------- K5: L4 distributed -------
__global__ __launch_bounds__(256) void k_l4(const float* __restrict__ h3g,
    const float* __restrict__ aW4,const float* __restrict__ ab4,
    const float* __restrict__ mW4,const float* __restrict__ mb4,
    float* __restrict__ h4g){
  int t=threadIdx.x, b=blockIdx.x, wave=t>>6, lane=t&63;
  int net=(b>=82);
  int r=(b-net*82)*4+wave;
  if(r>=325) return;
  const float* w=(net?mW4:aW4)+(size_t)r*270;
  const float* in=h3g+net*270;
  float a=0.f;
  for(int c=lane;c<270;c+=64) a+=w[c]*in[c];
  for(int off=32;off>0;off>>=1) a+=__shfl_down(a,off,64);
  if(lane==0) h4g[net*325+r]=a+(net?mb4:ab4)[r];
}

// ------- K6: redundant fin prologue + normalize rw/ww + new_memory -------
__global__ __launch_bounds__(256) void k_memupd(const float* __restrict__ M,
                         float* __restrict__ w_r, float* __restrict__ w_w,
                         const float* __restrict__ P, const ull* __restrict__ acc,
                         const float* __restrict__ h4g,
                         const float* __restrict__ Wv, const float* __restrict__ bv,
                         float* __restrict__ out, float* __restrict__ nm){
  __shared__ float4 ld[1280];
  __shared__ float probA[325], probB[325], outv[325], red[256];
  __shared__ float af[20], er[20], sc[2];
  int t=threadIdx.x, b=blockIdx.x, wave=t>>6, lane=t&63;
  // --- fin prologue (redundant per block, deterministic) ---
  {
    float v0=h4g[t], v1=(t<69)?h4g[256+t]:-3.0e38f;
    red[t]=fmaxf(v0,v1); __syncthreads();
    for(int o=128;o>0;o>>=1){ if(t<o) red[t]=fmaxf(red[t],red[t+o]); __syncthreads(); }
    if(t==0) sc[0]=red[0]; __syncthreads();
    float e0=expf(v0-sc[0]), e1=(t<69)?expf(v1-sc[0]):0.f;
    red[t]=e0+e1; __syncthreads();
    for(int o=128;o>0;o>>=1){ if(t<o) red[t]+=red[t+o]; __syncthreads(); }
    if(t==0) sc[1]=red[0]; __syncthreads();
    probA[t]=e0/sc[1]; if(t<69) probA[256+t]=e1/sc[1];
    __syncthreads();
    float y0=h4g[325+t], y1=(t<69)?h4g[325+256+t]:-3.0e38f;
    red[t]=fmaxf(y0,y1); __syncthreads();
    for(int o=128;o>0;o>>=1){ if(t<o) red[t]=fmaxf(red[t],red[t+o]); __syncthreads(); }
    if(t==0) sc[0]=red[0]; __syncthreads();
    float f0=expf(y0-sc[0]), f1=(t<69)?expf(y1-sc[0]):0.f;
    red[t]=f0+f1; __syncthreads();
    for(int o=128;o>0;o>>=1){ if(t<o) red[t]+=red[t+o]; __syncthreads(); }
    if(t==0) sc[1]=red[0]; __syncthreads();
    probB[t]=f0/sc[1]; if(t<69) probB[256+t]=f1/sc[1];
    __syncthreads();
    float ah0=P[105], ah1=P[106];
    outv[t]=ah0*probA[t]+ah1*probB[t];
    if(t<69) outv[256+t]=ah0*probA[256+t]+ah1*probB[256+t];
    if(b==0){ out[OUT_OFF+t]=outv[t]; if(t<69) out[OUT_OFF+256+t]=outv[256+t]; }
    if(t<20) er[t]=P[64+t];
    __syncthreads();
    float rho=P[104];
    for(int r=wave; r<20; r+=4){
      const float* w=Wv+(size_t)r*325;
      float a=0.f;
      for(int c=lane;c<325;c+=64) a+=w[c]*outv[c];
      for(int off=32;off>0;off>>=1) a+=__shfl_down(a,off,64);
      if(lane==0) af[r]=rho*P[84+r]+(1.0f-rho)*(a+bv[r]);
    }
    __syncthreads();
  }
  float Zr=(float)(decfx(acc[20])+1e-16), Zw=(float)(decfx(acc[21])+1e-16);
  const float4* Mf4=(const float4*)M;
  float4* nmf4=(float4*)nm;
  for(int p=0;p<4;p++){
    int rb=b*1024+p*256;
    size_t f4b=(size_t)rb*5;
#pragma unroll
    for(int k=0;k<5;k++){
      size_t idx=f4b+(size_t)(k*256+t);
      if(idx<NF4) ld[k*256+t]=Mf4[idx];
    }
    __syncthreads();
    int i=rb+t;
    if(i<NN){
      float wrn=w_r[i]/Zr;
      float wwn=w_w[i]/Zw;
      w_r[i]=wrn; w_w[i]=wwn;
#pragma unroll
      for(int q=0;q<5;q++){
        float4 v=ld[t*5+q];
        float4 o;
        o.x=v.x*(1.0f-wwn*er[4*q+0])+wwn*af[4*q+0];
        o.y=v.y*(1.0f-wwn*er[4*q+1])+wwn*af[4*q+1];
        o.z=v.z*(1.0f-wwn*er[4*q+2])+wwn*af[4*q+2];
        o.w=v.w*(1.0f-wwn*er[4*q+3])+wwn*af[4*q+3];
        ld[t*5+q]=o;
      }
    }
    __syncthreads();
#pragma unroll
    for(int k=0;k<5;k++){
      size_t idx=f4b+(size_t)(k*256+t);
      if(idx<NF4) nmf4[idx]=ld[k*256+t];
    }
    __syncthreads();
  }
}

extern "C" void kernel_launch(void* const* d_in, const int* in_sizes, int n_in,
                              void* d_out, int out_size, void* d_ws, size_t ws_size,
                              hipStream_t stream) {
  const float* X    =(const float*)d_in[0];
  const float* rwp  =(const float*)d_in[1];
  const float* wwp  =(const float*)d_in[2];
  const float* Mem  =(const float*)d_in[3];
  const float* rhd  =(const float*)d_in[4];
  const float* W1   =(const float*)d_in[5];
  const float* b1   =(const float*)d_in[6];
  const float* W2   =(const float*)d_in[7];
  const float* b2   =(const float*)d_in[8];
  const float* Wxi  =(const float*)d_in[9];
  const float* bxi  =(const float*)d_in[10];
  const float* Wz   =(const float*)d_in[11];
  const float* bz   =(const float*)d_in[12];
  const float* Wv   =(const float*)d_in[13];
  const float* bv   =(const float*)d_in[14];
  const float* aW1  =(const float*)d_in[15];
  const float* ab1  =(const float*)d_in[16];
  const float* aW2  =(const float*)d_in[17];
  const float* ab2  =(const float*)d_in[18];
  const float* aW3  =(const float*)d_in[19];
  const float* ab3  =(const float*)d_in[20];
  const float* aW4  =(const float*)d_in[21];
  const float* ab4  =(const float*)d_in[22];
  const float* mW1  =(const float*)d_in[23];
  const float* mb1  =(const float*)d_in[24];
  const float* mW2  =(const float*)d_in[25];
  const float* mb2  =(const float*)d_in[26];
  const float* mW3  =(const float*)d_in[27];
  const float* mb3  =(const float*)d_in[28];
  const float* mW4  =(const float*)d_in[29];
  const float* mb4  =(const float*)d_in[30];

  float* out = (float*)d_out;
  char* ws = (char*)d_ws;
  float*  P   = (float*)(ws + 0);        // 256 floats
  ull*    acc = (ull*)  (ws + 2048);     // 24 u64 fixed-point accumulators
  float*  h2g = (float*)(ws + 4096);     // 380
  float*  h3g = (float*)(ws + 8192);     // 540
  float*  h4g = (float*)(ws + 12288);    // 650
  float4* pms = (float4*)(ws + 16384);   // NB float4 (~15.6 KB)

  float2* sc2 = (float2*)(out + NM_OFF);   // scores staged in dead nm region
  float*  w_r = out + RW_OFF;              // unnormalized until k_memupd
  float*  w_w = out + WW_OFF;
  float*  nm  = out + NM_OFF;

  k_scores<<<NB,256,0,stream>>>(X,W1,b1,W2,b2,Wxi,bxi,Wz,bz,Mem,P,acc,sc2,pms);
  k_shift<<<NB,256,0,stream>>>(sc2,rwp,wwp,Mem,P,pms,w_r,w_w,acc);
  k_l12<<<96,256,0,stream>>>(acc,rhd,aW1,ab1,mW1,mb1,aW2,ab2,mW2,mb2,out,h2g);
  k_l3<<<136,256,0,stream>>>(h2g,aW3,ab3,mW3,mb3,h3g);
  k_l4<<<164,256,0,stream>>>(h3g,aW4,ab4,mW4,mb4,h4g);
  k_memupd<<<NB,256,0,stream>>>(Mem,w_r,w_w,P,acc,h4g,Wv,bv,out,nm);
}

// Round 8
// 137.039 us; speedup vs baseline: 1.2980x; 1.0187x over previous
//
#include <hip/hip_runtime.h>
#include <math.h>

#define NN 1000000
#define NF4 5000000       // NN*5 float4s in Memory
#define WD 20
#define NB 977            // blocks of 1024 rows
#define PST 1024          // pnrhT column stride

// d_out layout (floats): out[325] | rw[NN] | ww[NN] | new_memory[NN*20] | nrh[20]
#define OUT_OFF 0
#define RW_OFF  325
#define WW_OFF  1000325
#define NM_OFF  2000325
#define NRH_OFF 22000325

__device__ __forceinline__ float sigmoidf_(float x){ return 1.0f/(1.0f+expf(-x)); }
__device__ __forceinline__ float softplusf_(float x){ return (x>30.f)?x:log1pf(expf(x)); }

// ------- K1: controller-head prologue (redundant per block) + cosine scores -------
// P layout: kr:0-19 gr:20 sr:21-23 gammar:24 betar:25 knr:26
//           kw:32-51 gw:52 sw:53-55 gammaw:56 betaw:57 knw:58
//           erase:64-83 addraw:84-103 rho:104 ah0:105 ah1:106
__global__ __launch_bounds__(256) void k_scores(
    const float* __restrict__ X,
    const float* __restrict__ W1, const float* __restrict__ b1,
    const float* __restrict__ W2, const float* __restrict__ b2,
    const float* __restrict__ Wxi, const float* __restrict__ bxi,
    const float* __restrict__ Wz, const float* __restrict__ bz,
    const float* __restrict__ M, float* __restrict__ Pg,
    float2* __restrict__ sc2, float4* __restrict__ pms){
  __shared__ float4 ld[1280];   // 20 KB
  __shared__ float h1[48], h2[72], xi[95], sP[132];
  int t=threadIdx.x, b=blockIdx.x;
  if(t<48){ float a=b1[t]; const float* w=W1+t*14; for(int c=0;c<14;c++) a+=X[c]*w[c]; h1[t]=a; }
  __syncthreads();
  if(t<72){ float a=b2[t]; const float* w=W2+t*48; for(int c=0;c<48;c++) a+=h1[c]*w[c]; h2[t]=a; }
  __syncthreads();
  if(t<92){ float a=bxi[t]; const float* w=Wxi+t*72; for(int c=0;c<72;c++) a+=h2[c]*w[c]; xi[t]=a; }
  else if(t<95){ int z=t-92; float a=bz[z]; const float* w=Wz+z*72; for(int c=0;c<72;c++) a+=h2[c]*w[c]; xi[92+z]=a; }
  __syncthreads();
  if(t<20){
    sP[0+t]  = tanhf(xi[t]);
    sP[32+t] = tanhf(xi[26+t]);
    sP[64+t] = sigmoidf_(xi[52+t]);
    sP[84+t] = tanhf(xi[72+t]);
  }
  __syncthreads();
  if(t==32){   // read-head scalars (wave 0)
    float g=sigmoidf_(xi[20]);
    float a0=xi[21],a1=xi[22],a2=xi[23];
    float mx=fmaxf(a0,fmaxf(a1,a2));
    float e0=expf(a0-mx),e1=expf(a1-mx),e2=expf(a2-mx),es=e0+e1+e2;
    float gamma=1.0f+softplusf_(xi[24]);
    float beta=softplusf_(xi[25]);
    float n2=0.f;
#pragma unroll
    for(int j=0;j<20;j++){ float ke=sP[j]+1e-16f; n2+=ke*ke; }
    sP[20]=g; sP[21]=e0/es; sP[22]=e1/es; sP[23]=e2/es; sP[24]=gamma; sP[25]=beta;
    sP[26]=fmaxf(sqrtf(n2),1e-8f);
  }
  if(t==96){   // write-head scalars (wave 1)
    float g=sigmoidf_(xi[46]);
    float a0=xi[47],a1=xi[48],a2=xi[49];
    float mx=fmaxf(a0,fmaxf(a1,a2));
    float e0=expf(a0-mx),e1=expf(a1-mx),e2=expf(a2-mx),es=e0+e1+e2;
    float gamma=1.0f+softplusf_(xi[50]);
    float beta=softplusf_(xi[51]);
    float n2=0.f;
#pragma unroll
    for(int j=0;j<20;j++){ float ke=sP[32+j]+1e-16f; n2+=ke*ke; }
    sP[52]=g; sP[53]=e0/es; sP[54]=e1/es; sP[55]=e2/es; sP[56]=gamma; sP[57]=beta;
    sP[58]=fmaxf(sqrtf(n2),1e-8f);
  }
  if(t==160){  // zeta scalars (wave 2)
    sP[104]=sigmoidf_(xi[92]);
    float mx=fmaxf(xi[93],xi[94]);
    float e1=expf(xi[93]-mx), e2=expf(xi[94]-mx);
    sP[105]=e1/(e1+e2); sP[106]=e2/(e1+e2);
  }
  __syncthreads();
  if(b==0 && t<132) Pg[t]=sP[t];
  float kr[20], kw[20];
#pragma unroll
  for(int j=0;j<20;j++){ kr[j]=sP[j]+1e-16f; kw[j]=sP[32+j]+1e-16f; }
  float betar=sP[25], betaw=sP[57], knr=sP[26], knw=sP[58];
  const float4* Mf4=(const float4*)M;
  float sR[4], sW[4];
  for(int p=0;p<4;p++){
    int rb=b*1024+p*256;
    size_t f4b=(size_t)rb*5;
#pragma unroll
    for(int k=0;k<5;k++){
      size_t idx=f4b+(size_t)(k*256+t);
      ld[k*256+t] = (idx<NF4)?Mf4[idx]:make_float4(0.f,0.f,0.f,0.f);
    }
    __syncthreads();
    int i=rb+t;
    float srv=-3.0e38f, swv=-3.0e38f;
    if(i<NN){
      float dr=0.f,dw=0.f,n2=0.f;
#pragma unroll
      for(int q=0;q<5;q++){
        float4 v=ld[t*5+q];
        float m0=v.x+1e-16f,m1=v.y+1e-16f,m2=v.z+1e-16f,m3=v.w+1e-16f;
        dr+=m0*kr[4*q]+m1*kr[4*q+1]+m2*kr[4*q+2]+m3*kr[4*q+3];
        dw+=m0*kw[4*q]+m1*kw[4*q+1]+m2*kw[4*q+2]+m3*kw[4*q+3];
        n2+=m0*m0+m1*m1+m2*m2+m3*m3;
      }
      float nm=fmaxf(sqrtf(n2),1e-8f);
      srv=betar*(dr/(nm*knr));
      swv=betaw*(dw/(nm*knw));
      sc2[i]=make_float2(srv,swv);
    }
    sR[p]=srv; sW[p]=swv;
    __syncthreads();
  }
  float* r1=(float*)ld; float* r2=r1+256;
  double* d1=(double*)(r1+512); double* d2=d1+256;
  float lm1=fmaxf(fmaxf(sR[0],sR[1]),fmaxf(sR[2],sR[3]));
  float lm2=fmaxf(fmaxf(sW[0],sW[1]),fmaxf(sW[2],sW[3]));
  r1[t]=lm1; r2[t]=lm2; __syncthreads();
  for(int o=128;o>0;o>>=1){ if(t<o){ r1[t]=fmaxf(r1[t],r1[t+o]); r2[t]=fmaxf(r2[t],r2[t+o]); } __syncthreads(); }
  float mb1=r1[0], mb2=r2[0]; __syncthreads();
  double s1=0.0,s2=0.0;
#pragma unroll
  for(int p=0;p<4;p++){ s1+=(double)expf(sR[p]-mb1); s2+=(double)expf(sW[p]-mb2); }
  d1[t]=s1; d2[t]=s2; __syncthreads();
  for(int o=128;o>0;o>>=1){ if(t<o){ d1[t]+=d1[t+o]; d2[t]+=d2[t+o]; } __syncthreads(); }
  if(t==0) pms[b]=make_float4(mb1,mb2,(float)d1[0],(float)d2[0]);
}

// ------- K2: interpolate+shift+pow; fused rw@M; per-block partial stores -------
__global__ __launch_bounds__(256) void k_shift(const float2* __restrict__ sc2,
                        const float* __restrict__ wpr, const float* __restrict__ wpw,
                        const float* __restrict__ M, const float* __restrict__ P,
                        const float4* __restrict__ pms,
                        float* __restrict__ w_r_out, float* __restrict__ w_w_out,
                        double* __restrict__ pZ, double* __restrict__ pnrhT){
  __shared__ float4 ld[1280];
  __shared__ float bmS[4];
  float* r1=(float*)ld; float* r2=r1+256;
  double* d1=(double*)(r1+512); double* d2=d1+256;
  float* wsum=(float*)(d2+256);  // [4][20]
  int t=threadIdx.x, b=blockIdx.x;
  float4 v4[4];
#pragma unroll
  for(int k=0;k<4;k++){
    int idx=t+k*256;
    v4[k] = (idx<NB) ? pms[idx] : make_float4(-3.0e38f,-3.0e38f,0.f,0.f);
  }
  float lm1=fmaxf(fmaxf(v4[0].x,v4[1].x),fmaxf(v4[2].x,v4[3].x));
  float lm2=fmaxf(fmaxf(v4[0].y,v4[1].y),fmaxf(v4[2].y,v4[3].y));
  r1[t]=lm1; r2[t]=lm2; __syncthreads();
  for(int o=128;o>0;o>>=1){ if(t<o){ r1[t]=fmaxf(r1[t],r1[t+o]); r2[t]=fmaxf(r2[t],r2[t+o]); } __syncthreads(); }
  if(t==0){ bmS[0]=r1[0]; bmS[1]=r2[0]; } __syncthreads();
  float mr=bmS[0], mw=bmS[1];
  double s1=0.0,s2=0.0;
#pragma unroll
  for(int k=0;k<4;k++){
    s1 += (double)v4[k].z * (double)expf(v4[k].x-mr);
    s2 += (double)v4[k].w * (double)expf(v4[k].y-mw);
  }
  d1[t]=s1; d2[t]=s2; __syncthreads();
  for(int o=128;o>0;o>>=1){ if(t<o){ d1[t]+=d1[t+o]; d2[t]+=d2[t+o]; } __syncthreads(); }
  if(t==0){ bmS[2]=(float)d1[0]; bmS[3]=(float)d2[0]; } __syncthreads();
  float Sr=bmS[2], Sw=bmS[3];
  float gr=P[20], s0r=P[21], s1r=P[22], s2r=P[23], gar=P[24];
  float gw=P[52], s0w=P[53], s1w=P[54], s2w=P[55], gaw=P[56];
  float omgr=1.0f-gr, omgw=1.0f-gw;
  const float4* Mf4=(const float4*)M;
  float acc[20];
#pragma unroll
  for(int j=0;j<20;j++) acc[j]=0.f;
  double zr=0.0, zw=0.0;
  for(int p=0;p<4;p++){
    int rb=b*1024+p*256;
    size_t f4b=(size_t)rb*5;
#pragma unroll
    for(int k=0;k<5;k++){
      size_t idx=f4b+(size_t)(k*256+t);
      ld[k*256+t] = (idx<NF4)?Mf4[idx]:make_float4(0.f,0.f,0.f,0.f);
    }
    __syncthreads();
    int i=rb+t;
    if(i<NN){
      int im1=(i==0)?(NN-1):(i-1);
      int ip1=(i==NN-1)?0:(i+1);
      float2 scm=sc2[im1], sc0=sc2[i], scp=sc2[ip1];
      float wgrm = gr*(expf(scm.x-mr)/Sr) + omgr*wpr[im1];
      float wgr0 = gr*(expf(sc0.x-mr)/Sr) + omgr*wpr[i  ];
      float wgrp = gr*(expf(scp.x-mr)/Sr) + omgr*wpr[ip1];
      float wgwm = gw*(expf(scm.y-mw)/Sw) + omgw*wpw[im1];
      float wgw0 = gw*(expf(sc0.y-mw)/Sw) + omgw*wpw[i  ];
      float wgwp = gw*(expf(scp.y-mw)/Sw) + omgw*wpw[ip1];
      float wr = powf(s0r*wgrm + s1r*wgr0 + s2r*wgrp, gar);
      float ww = powf(s0w*wgwm + s1w*wgw0 + s2w*wgwp, gaw);
      w_r_out[i]=wr; w_w_out[i]=ww;
      zr+=(double)wr; zw+=(double)ww;
#pragma unroll
      for(int q=0;q<5;q++){
        float4 mv=ld[t*5+q];
        acc[4*q+0]+=wr*mv.x; acc[4*q+1]+=wr*mv.y; acc[4*q+2]+=wr*mv.z; acc[4*q+3]+=wr*mv.w;
      }
    }
    __syncthreads();
  }
  d1[t]=zr; d2[t]=zw; __syncthreads();
  for(int o=128;o>0;o>>=1){ if(t<o){ d1[t]+=d1[t+o]; d2[t]+=d2[t+o]; } __syncthreads(); }
  if(t==0){ pZ[2*b]=d1[0]; pZ[2*b+1]=d2[0]; }
  __syncthreads();
#pragma unroll
  for(int j=0;j<20;j++){
    for(int off=32;off>0;off>>=1) acc[j]+=__shfl_down(acc[j],off,64);
  }
  int wave=t>>6, lane=t&63;
  if(lane==0){
#pragma unroll
    for(int j=0;j<20;j++) wsum[wave*20+j]=acc[j];
  }
  __syncthreads();
  if(t<20){
    double s=(double)wsum[0*20+t]+(double)wsum[1*20+t]+(double)wsum[2*20+t]+(double)wsum[3*20+t];
    pnrhT[(size_t)t*PST+b]=s;
  }
}

// ------- K3: redundant {pZ/pnrhT reduce + in40 + L1} + distributed L2 -------
__global__ __launch_bounds__(256) void k_l12(
    const double* __restrict__ pZ, const double* __restrict__ pnrhT,
    const float* __restrict__ read_head,
    const float* __restrict__ aW1,const float* __restrict__ ab1,
    const float* __restrict__ mW1,const float* __restrict__ mb1,
    const float* __restrict__ aW2,const float* __restrict__ ab2,
    const float* __restrict__ mW2,const float* __restrict__ mb2,
    float* __restrict__ out, float* __restrict__ h2g, double* __restrict__ Sd){
  __shared__ float in40[40], h1s[110];
  __shared__ double dred[24];
  int t=threadIdx.x, b=blockIdx.x, wave=t>>6, lane=t&63;
  int net=(b>=48);
  // redundant fixed-tree reduce of 22 columns (deterministic, identical per block)
  for(int j=wave; j<22; j+=4){
    double s=0.0;
    if(j<20){
      const double* src=pnrhT+(size_t)j*PST;
      for(int idx=lane; idx<NB; idx+=64) s+=src[idx];
    } else {
      for(int idx=lane; idx<NB; idx+=64) s+=pZ[2*idx+(j-20)];
    }
    for(int off=32;off>0;off>>=1) s+=__shfl_down(s,off,64);
    if(lane==0) dred[j]=s;
  }
  __syncthreads();
  if(t<20){
    double Zr=dred[20]+1e-16;
    float nv=(float)(dred[t]/Zr);
    in40[20+t]=nv; in40[t]=read_head[t];
    if(b==0) out[NRH_OFF+t]=nv;
  }
  if(b==0 && t==21){ Sd[0]=dred[20]; Sd[1]=dred[21]; }
  __syncthreads();
  int g=t>>4, l16=t&15;
  const float* W1=net?mW1:aW1; const float* B1=net?mb1:ab1;
  for(int pass=0; pass<7; ++pass){
    int r=pass*16+g;
    if(r<110){
      const float* w=W1+(size_t)r*40;
      float a=0.f;
      for(int c=l16;c<40;c+=16) a+=w[c]*in40[c];
      a+=__shfl_xor(a,8,64); a+=__shfl_xor(a,4,64); a+=__shfl_xor(a,2,64); a+=__shfl_xor(a,1,64);
      if(l16==0) h1s[r]=fmaxf(a+B1[r],0.f);
    }
  }
  __syncthreads();
  int r=(b-net*48)*4+wave;
  if(r<190){
    const float* w=(net?mW2:aW2)+(size_t)r*110;
    float a=0.f;
    for(int c=lane;c<110;c+=64) a+=w[c]*h1s[c];
    for(int off=32;off>0;off>>=1) a+=__shfl_down(a,off,64);
    if(lane==0) h2g[net*190+r]=fmaxf(a+(net?mb2:ab2)[r],0.f);
  }
}

// ------- K4: L3 distributed -------
__global__ __launch_bounds__(256) void k_l3(const float* __restrict__ h2g,
    const float* __restrict__ aW3,const float* __restrict__ ab3,
    const float* __restrict__ mW3,const float* __restrict__ mb3,
    float* __restrict__ h3g){
  int t=threadIdx.x, b=blockIdx.x, wave=t>>6, lane=t&63;
  int net=(b>=68);
  int r=(b-net*68)*4+wave;
  if(r>=270) return;
  const float* w=(net?mW3:aW3)+(size_t)r*190;
  const float* in=h2g+net*190;
  float a=0.f;
  for(int c=lane;c<190;c+=64) a+=w[c]*in[c];
  for(int off=32;off>0;off>>=1) a+=__shfl_down(a,off,64);
  if(lane==0) h3g[net*270+r]=fmaxf(a+(net?mb3:ab3)[r],0.f);
}

// ------- K5: L4 distributed -------
__global__ __launch_bounds__(256) void k_l4(const float* __restrict__ h3g,
    const float* __restrict__ aW4,const float* __restrict__ ab4,
    const float* __restrict__ mW4,const float* __restrict__ mb4,
    float* __restrict__ h4g){
  int t=threadIdx.x, b=blockIdx.x, wave=t>>6, lane=t&63;
  int net=(b>=82);
  int r=(b-net*82)*4+wave;
  if(r>=325) return;
  const float* w=(net?mW4:aW4)+(size_t)r*270;
  const float* in=h3g+net*270;
  float a=0.f;
  for(int c=lane;c<270;c+=64) a+=w[c]*in[c];
  for(int off=32;off>0;off>>=1) a+=__shfl_down(a,off,64);
  if(lane==0) h4g[net*325+r]=a+(net?mb4:ab4)[r];
}

// ------- K6: redundant fin prologue + normalize rw/ww + new_memory -------
__global__ __launch_bounds__(256) void k_memupd(const float* __restrict__ M,
                         float* __restrict__ w_r, float* __restrict__ w_w,
                         const float* __restrict__ P, const double* __restrict__ Sd,
                         const float* __restrict__ h4g,
                         const float* __restrict__ Wv, const float* __restrict__ bv,
                         float* __restrict__ out, float* __restrict__ nm){
  __shared__ float4 ld[1280];
  __shared__ float probA[325], probB[325], outv[325], red[256];
  __shared__ float af[20], er[20], sc[2];
  int t=threadIdx.x, b=blockIdx.x, wave=t>>6, lane=t&63;
  // --- fin prologue (redundant per block, deterministic) ---
  {
    float v0=h4g[t], v1=(t<69)?h4g[256+t]:-3.0e38f;
    red[t]=fmaxf(v0,v1); __syncthreads();
    for(int o=128;o>0;o>>=1){ if(t<o) red[t]=fmaxf(red[t],red[t+o]); __syncthreads(); }
    if(t==0) sc[0]=red[0]; __syncthreads();
    float e0=expf(v0-sc[0]), e1=(t<69)?expf(v1-sc[0]):0.f;
    red[t]=e0+e1; __syncthreads();
    for(int o=128;o>0;o>>=1){ if(t<o) red[t]+=red[t+o]; __syncthreads(); }
    if(t==0) sc[1]=red[0]; __syncthreads();
    probA[t]=e0/sc[1]; if(t<69) probA[256+t]=e1/sc[1];
    __syncthreads();
    float y0=h4g[325+t], y1=(t<69)?h4g[325+256+t]:-3.0e38f;
    red[t]=fmaxf(y0,y1); __syncthreads();
    for(int o=128;o>0;o>>=1){ if(t<o) red[t]=fmaxf(red[t],red[t+o]); __syncthreads(); }
    if(t==0) sc[0]=red[0]; __syncthreads();
    float f0=expf(y0-sc[0]), f1=(t<69)?expf(y1-sc[0]):0.f;
    red[t]=f0+f1; __syncthreads();
    for(int o=128;o>0;o>>=1){ if(t<o) red[t]+=red[t+o]; __syncthreads(); }
    if(t==0) sc[1]=red[0]; __syncthreads();
    probB[t]=f0/sc[1]; if(t<69) probB[256+t]=f1/sc[1];
    __syncthreads();
    float ah0=P[105], ah1=P[106];
    outv[t]=ah0*probA[t]+ah1*probB[t];
    if(t<69) outv[256+t]=ah0*probA[256+t]+ah1*probB[256+t];
    if(b==0){ out[OUT_OFF+t]=outv[t]; if(t<69) out[OUT_OFF+256+t]=outv[256+t]; }
    if(t<20) er[t]=P[64+t];
    __syncthreads();
    float rho=P[104];
    for(int r=wave; r<20; r+=4){
      const float* w=Wv+(size_t)r*325;
      float a=0.f;
      for(int c=lane;c<325;c+=64) a+=w[c]*outv[c];
      for(int off=32;off>0;off>>=1) a+=__shfl_down(a,off,64);
      if(lane==0) af[r]=rho*P[84+r]+(1.0f-rho)*(a+bv[r]);
    }
    __syncthreads();
  }
  float Zr=(float)(Sd[0]+1e-16), Zw=(float)(Sd[1]+1e-16);
  const float4* Mf4=(const float4*)M;
  float4* nmf4=(float4*)nm;
  for(int p=0;p<4;p++){
    int rb=b*1024+p*256;
    size_t f4b=(size_t)rb*5;
#pragma unroll
    for(int k=0;k<5;k++){
      size_t idx=f4b+(size_t)(k*256+t);
      if(idx<NF4) ld[k*256+t]=Mf4[idx];
    }
    __syncthreads();
    int i=rb+t;
    if(i<NN){
      float wrn=w_r[i]/Zr;
      float wwn=w_w[i]/Zw;
      w_r[i]=wrn; w_w[i]=wwn;
#pragma unroll
      for(int q=0;q<5;q++){
        float4 v=ld[t*5+q];
        float4 o;
        o.x=v.x*(1.0f-wwn*er[4*q+0])+wwn*af[4*q+0];
        o.y=v.y*(1.0f-wwn*er[4*q+1])+wwn*af[4*q+1];
        o.z=v.z*(1.0f-wwn*er[4*q+2])+wwn*af[4*q+2];
        o.w=v.w*(1.0f-wwn*er[4*q+3])+wwn*af[4*q+3];
        ld[t*5+q]=o;
      }
    }
    __syncthreads();
#pragma unroll
    for(int k=0;k<5;k++){
      size_t idx=f4b+(size_t)(k*256+t);
      if(idx<NF4) nmf4[idx]=ld[k*256+t];
    }
    __syncthreads();
  }
}

extern "C" void kernel_launch(void* const* d_in, const int* in_sizes, int n_in,
                              void* d_out, int out_size, void* d_ws, size_t ws_size,
                              hipStream_t stream) {
  const float* X    =(const float*)d_in[0];
  const float* rwp  =(const float*)d_in[1];
  const float* wwp  =(const float*)d_in[2];
  const float* Mem  =(const float*)d_in[3];
  const float* rhd  =(const float*)d_in[4];
  const float* W1   =(const float*)d_in[5];
  const float* b1   =(const float*)d_in[6];
  const float* W2   =(const float*)d_in[7];
  const float* b2   =(const float*)d_in[8];
  const float* Wxi  =(const float*)d_in[9];
  const float* bxi  =(const float*)d_in[10];
  const float* Wz   =(const float*)d_in[11];
  const float* bz   =(const float*)d_in[12];
  const float* Wv   =(const float*)d_in[13];
  const float* bv   =(const float*)d_in[14];
  const float* aW1  =(const float*)d_in[15];
  const float* ab1  =(const float*)d_in[16];
  const float* aW2  =(const float*)d_in[17];
  const float* ab2  =(const float*)d_in[18];
  const float* aW3  =(const float*)d_in[19];
  const float* ab3  =(const float*)d_in[20];
  const float* aW4  =(const float*)d_in[21];
  const float* ab4  =(const float*)d_in[22];
  const float* mW1  =(const float*)d_in[23];
  const float* mb1  =(const float*)d_in[24];
  const float* mW2  =(const float*)d_in[25];
  const float* mb2  =(const float*)d_in[26];
  const float* mW3  =(const float*)d_in[27];
  const float* mb3  =(const float*)d_in[28];
  const float* mW4  =(const float*)d_in[29];
  const float* mb4  =(const float*)d_in[30];

  float* out = (float*)d_out;
  char* ws = (char*)d_ws;
  float*  P   = (float*)(ws + 0);        // 256 floats
  double* Sd  = (double*)(ws + 2048);    // Z_r, Z_w
  float*  h2g = (float*)(ws + 4096);     // 380
  float*  h3g = (float*)(ws + 8192);     // 540
  float*  h4g = (float*)(ws + 12288);    // 650
  float4* pms = (float4*)(ws + 16384);   // NB float4 (~15.6 KB)
  double* pZ  = (double*)(ws + 65536);   // NB*2 (~15.6 KB)
  double* pnrhT=(double*)(ws + 131072);  // 20*PST doubles (160 KB)

  float2* sc2 = (float2*)(out + NM_OFF);   // scores staged in dead nm region
  float*  w_r = out + RW_OFF;              // unnormalized until k_memupd
  float*  w_w = out + WW_OFF;
  float*  nm  = out + NM_OFF;

  k_scores<<<NB,256,0,stream>>>(X,W1,b1,W2,b2,Wxi,bxi,Wz,bz,Mem,P,sc2,pms);
  k_shift<<<NB,256,0,stream>>>(sc2,rwp,wwp,Mem,P,pms,w_r,w_w,pZ,pnrhT);
  k_l12<<<96,256,0,stream>>>(pZ,pnrhT,rhd,aW1,ab1,mW1,mb1,aW2,ab2,mW2,mb2,out,h2g,Sd);
  k_l3<<<136,256,0,stream>>>(h2g,aW3,ab3,mW3,mb3,h3g);
  k_l4<<<164,256,0,stream>>>(h3g,aW4,ab4,mW4,mb4,h4g);
  k_memupd<<<NB,256,0,stream>>>(Mem,w_r,w_w,P,Sd,h4g,Wv,bv,out,nm);
}

// Round 9
// 130.477 us; speedup vs baseline: 1.3633x; 1.0503x over previous
//
#include <hip/hip_runtime.h>
#include <math.h>

#define NN 1000000
#define NF4 5000000       // NN*5 float4s in Memory
#define WD 20
#define NB 977            // blocks of 1024 rows
#define PST 1024          // pnrhT column stride

// d_out layout (floats): out[325] | rw[NN] | ww[NN] | new_memory[NN*20] | nrh[20]
#define OUT_OFF 0
#define RW_OFF  325
#define WW_OFF  1000325
#define NM_OFF  2000325
#define NRH_OFF 22000325

__device__ __forceinline__ float sigmoidf_(float x){ return 1.0f/(1.0f+expf(-x)); }
__device__ __forceinline__ float softplusf_(float x){ return (x>30.f)?x:log1pf(expf(x)); }

// ------- K1: controller-head prologue (redundant per block) + cosine scores -------
// P layout: kr:0-19 gr:20 sr:21-23 gammar:24 betar:25 knr:26
//           kw:32-51 gw:52 sw:53-55 gammaw:56 betaw:57 knw:58
//           erase:64-83 addraw:84-103 rho:104 ah0:105 ah1:106 addf:112-131
__global__ __launch_bounds__(256) void k_scores(
    const float* __restrict__ X,
    const float* __restrict__ W1, const float* __restrict__ b1,
    const float* __restrict__ W2, const float* __restrict__ b2,
    const float* __restrict__ Wxi, const float* __restrict__ bxi,
    const float* __restrict__ Wz, const float* __restrict__ bz,
    const float* __restrict__ M, float* __restrict__ Pg,
    float2* __restrict__ sc2, float4* __restrict__ pms){
  __shared__ float4 ld[1280];   // 20 KB
  __shared__ float h1[48], h2[72], xi[95], sP[132];
  int t=threadIdx.x, b=blockIdx.x;
  if(t<48){ float a=b1[t]; const float* w=W1+t*14; for(int c=0;c<14;c++) a+=X[c]*w[c]; h1[t]=a; }
  __syncthreads();
  if(t<72){ float a=b2[t]; const float* w=W2+t*48; for(int c=0;c<48;c++) a+=h1[c]*w[c]; h2[t]=a; }
  __syncthreads();
  if(t<92){ float a=bxi[t]; const float* w=Wxi+t*72; for(int c=0;c<72;c++) a+=h2[c]*w[c]; xi[t]=a; }
  else if(t<95){ int z=t-92; float a=bz[z]; const float* w=Wz+z*72; for(int c=0;c<72;c++) a+=h2[c]*w[c]; xi[92+z]=a; }
  __syncthreads();
  if(t<20){
    sP[0+t]  = tanhf(xi[t]);
    sP[32+t] = tanhf(xi[26+t]);
    sP[64+t] = sigmoidf_(xi[52+t]);
    sP[84+t] = tanhf(xi[72+t]);
  }
  __syncthreads();
  if(t==32){   // read-head scalars (wave 0)
    float g=sigmoidf_(xi[20]);
    float a0=xi[21],a1=xi[22],a2=xi[23];
    float mx=fmaxf(a0,fmaxf(a1,a2));
    float e0=expf(a0-mx),e1=expf(a1-mx),e2=expf(a2-mx),es=e0+e1+e2;
    float gamma=1.0f+softplusf_(xi[24]);
    float beta=softplusf_(xi[25]);
    float n2=0.f;
#pragma unroll
    for(int j=0;j<20;j++){ float ke=sP[j]+1e-16f; n2+=ke*ke; }
    sP[20]=g; sP[21]=e0/es; sP[22]=e1/es; sP[23]=e2/es; sP[24]=gamma; sP[25]=beta;
    sP[26]=fmaxf(sqrtf(n2),1e-8f);
  }
  if(t==96){   // write-head scalars (wave 1)
    float g=sigmoidf_(xi[46]);
    float a0=xi[47],a1=xi[48],a2=xi[49];
    float mx=fmaxf(a0,fmaxf(a1,a2));
    float e0=expf(a0-mx),e1=expf(a1-mx),e2=expf(a2-mx),es=e0+e1+e2;
    float gamma=1.0f+softplusf_(xi[50]);
    float beta=softplusf_(xi[51]);
    float n2=0.f;
#pragma unroll
    for(int j=0;j<20;j++){ float ke=sP[32+j]+1e-16f; n2+=ke*ke; }
    sP[52]=g; sP[53]=e0/es; sP[54]=e1/es; sP[55]=e2/es; sP[56]=gamma; sP[57]=beta;
    sP[58]=fmaxf(sqrtf(n2),1e-8f);
  }
  if(t==160){  // zeta scalars (wave 2)
    sP[104]=sigmoidf_(xi[92]);
    float mx=fmaxf(xi[93],xi[94]);
    float e1=expf(xi[93]-mx), e2=expf(xi[94]-mx);
    sP[105]=e1/(e1+e2); sP[106]=e2/(e1+e2);
  }
  __syncthreads();
  if(b==0 && t<132) Pg[t]=sP[t];
  float kr[20], kw[20];
#pragma unroll
  for(int j=0;j<20;j++){ kr[j]=sP[j]+1e-16f; kw[j]=sP[32+j]+1e-16f; }
  float betar=sP[25], betaw=sP[57], knr=sP[26], knw=sP[58];
  const float4* Mf4=(const float4*)M;
  float sR[4], sW[4];
  for(int p=0;p<4;p++){
    int rb=b*1024+p*256;
    size_t f4b=(size_t)rb*5;
#pragma unroll
    for(int k=0;k<5;k++){
      size_t idx=f4b+(size_t)(k*256+t);
      ld[k*256+t] = (idx<NF4)?Mf4[idx]:make_float4(0.f,0.f,0.f,0.f);
    }
    __syncthreads();
    int i=rb+t;
    float srv=-3.0e38f, swv=-3.0e38f;
    if(i<NN){
      float dr=0.f,dw=0.f,n2=0.f;
#pragma unroll
      for(int q=0;q<5;q++){
        float4 v=ld[t*5+q];
        float m0=v.x+1e-16f,m1=v.y+1e-16f,m2=v.z+1e-16f,m3=v.w+1e-16f;
        dr+=m0*kr[4*q]+m1*kr[4*q+1]+m2*kr[4*q+2]+m3*kr[4*q+3];
        dw+=m0*kw[4*q]+m1*kw[4*q+1]+m2*kw[4*q+2]+m3*kw[4*q+3];
        n2+=m0*m0+m1*m1+m2*m2+m3*m3;
      }
      float nm=fmaxf(sqrtf(n2),1e-8f);
      srv=betar*(dr/(nm*knr));
      swv=betaw*(dw/(nm*knw));
      sc2[i]=make_float2(srv,swv);
    }
    sR[p]=srv; sW[p]=swv;
    __syncthreads();
  }
  float* r1=(float*)ld; float* r2=r1+256;
  double* d1=(double*)(r1+512); double* d2=d1+256;
  float lm1=fmaxf(fmaxf(sR[0],sR[1]),fmaxf(sR[2],sR[3]));
  float lm2=fmaxf(fmaxf(sW[0],sW[1]),fmaxf(sW[2],sW[3]));
  r1[t]=lm1; r2[t]=lm2; __syncthreads();
  for(int o=128;o>0;o>>=1){ if(t<o){ r1[t]=fmaxf(r1[t],r1[t+o]); r2[t]=fmaxf(r2[t],r2[t+o]); } __syncthreads(); }
  float mb1=r1[0], mb2=r2[0]; __syncthreads();
  double s1=0.0,s2=0.0;
#pragma unroll
  for(int p=0;p<4;p++){ s1+=(double)expf(sR[p]-mb1); s2+=(double)expf(sW[p]-mb2); }
  d1[t]=s1; d2[t]=s2; __syncthreads();
  for(int o=128;o>0;o>>=1){ if(t<o){ d1[t]+=d1[t+o]; d2[t]+=d2[t+o]; } __syncthreads(); }
  if(t==0) pms[b]=make_float4(mb1,mb2,(float)d1[0],(float)d2[0]);
}

// ------- K2: interpolate+shift+pow; fused rw@M; per-block partial stores -------
__global__ __launch_bounds__(256) void k_shift(const float2* __restrict__ sc2,
                        const float* __restrict__ wpr, const float* __restrict__ wpw,
                        const float* __restrict__ M, const float* __restrict__ P,
                        const float4* __restrict__ pms,
                        float* __restrict__ w_r_out, float* __restrict__ w_w_out,
                        double* __restrict__ pZ, double* __restrict__ pnrhT){
  __shared__ float4 ld[1280];
  __shared__ float bmS[4];
  float* r1=(float*)ld; float* r2=r1+256;
  double* d1=(double*)(r1+512); double* d2=d1+256;
  float* wsum=(float*)(d2+256);  // [4][20]
  int t=threadIdx.x, b=blockIdx.x;
  float4 v4[4];
#pragma unroll
  for(int k=0;k<4;k++){
    int idx=t+k*256;
    v4[k] = (idx<NB) ? pms[idx] : make_float4(-3.0e38f,-3.0e38f,0.f,0.f);
  }
  float lm1=fmaxf(fmaxf(v4[0].x,v4[1].x),fmaxf(v4[2].x,v4[3].x));
  float lm2=fmaxf(fmaxf(v4[0].y,v4[1].y),fmaxf(v4[2].y,v4[3].y));
  r1[t]=lm1; r2[t]=lm2; __syncthreads();
  for(int o=128;o>0;o>>=1){ if(t<o){ r1[t]=fmaxf(r1[t],r1[t+o]); r2[t]=fmaxf(r2[t],r2[t+o]); } __syncthreads(); }
  if(t==0){ bmS[0]=r1[0]; bmS[1]=r2[0]; } __syncthreads();
  float mr=bmS[0], mw=bmS[1];
  double s1=0.0,s2=0.0;
#pragma unroll
  for(int k=0;k<4;k++){
    s1 += (double)v4[k].z * (double)expf(v4[k].x-mr);
    s2 += (double)v4[k].w * (double)expf(v4[k].y-mw);
  }
  d1[t]=s1; d2[t]=s2; __syncthreads();
  for(int o=128;o>0;o>>=1){ if(t<o){ d1[t]+=d1[t+o]; d2[t]+=d2[t+o]; } __syncthreads(); }
  if(t==0){ bmS[2]=(float)d1[0]; bmS[3]=(float)d2[0]; } __syncthreads();
  float Sr=bmS[2], Sw=bmS[3];
  float gr=P[20], s0r=P[21], s1r=P[22], s2r=P[23], gar=P[24];
  float gw=P[52], s0w=P[53], s1w=P[54], s2w=P[55], gaw=P[56];
  float omgr=1.0f-gr, omgw=1.0f-gw;
  const float4* Mf4=(const float4*)M;
  float acc[20];
#pragma unroll
  for(int j=0;j<20;j++) acc[j]=0.f;
  double zr=0.0, zw=0.0;
  for(int p=0;p<4;p++){
    int rb=b*1024+p*256;
    size_t f4b=(size_t)rb*5;
#pragma unroll
    for(int k=0;k<5;k++){
      size_t idx=f4b+(size_t)(k*256+t);
      ld[k*256+t] = (idx<NF4)?Mf4[idx]:make_float4(0.f,0.f,0.f,0.f);
    }
    __syncthreads();
    int i=rb+t;
    if(i<NN){
      int im1=(i==0)?(NN-1):(i-1);
      int ip1=(i==NN-1)?0:(i+1);
      float2 scm=sc2[im1], sc0=sc2[i], scp=sc2[ip1];
      float wgrm = gr*(expf(scm.x-mr)/Sr) + omgr*wpr[im1];
      float wgr0 = gr*(expf(sc0.x-mr)/Sr) + omgr*wpr[i  ];
      float wgrp = gr*(expf(scp.x-mr)/Sr) + omgr*wpr[ip1];
      float wgwm = gw*(expf(scm.y-mw)/Sw) + omgw*wpw[im1];
      float wgw0 = gw*(expf(sc0.y-mw)/Sw) + omgw*wpw[i  ];
      float wgwp = gw*(expf(scp.y-mw)/Sw) + omgw*wpw[ip1];
      float wr = powf(s0r*wgrm + s1r*wgr0 + s2r*wgrp, gar);
      float ww = powf(s0w*wgwm + s1w*wgw0 + s2w*wgwp, gaw);
      w_r_out[i]=wr; w_w_out[i]=ww;
      zr+=(double)wr; zw+=(double)ww;
#pragma unroll
      for(int q=0;q<5;q++){
        float4 mv=ld[t*5+q];
        acc[4*q+0]+=wr*mv.x; acc[4*q+1]+=wr*mv.y; acc[4*q+2]+=wr*mv.z; acc[4*q+3]+=wr*mv.w;
      }
    }
    __syncthreads();
  }
  d1[t]=zr; d2[t]=zw; __syncthreads();
  for(int o=128;o>0;o>>=1){ if(t<o){ d1[t]+=d1[t+o]; d2[t]+=d2[t+o]; } __syncthreads(); }
  if(t==0){ pZ[2*b]=d1[0]; pZ[2*b+1]=d2[0]; }
  __syncthreads();
#pragma unroll
  for(int j=0;j<20;j++){
    for(int off=32;off>0;off>>=1) acc[j]+=__shfl_down(acc[j],off,64);
  }
  int wave=t>>6, lane=t&63;
  if(lane==0){
#pragma unroll
    for(int j=0;j<20;j++) wsum[wave*20+j]=acc[j];
  }
  __syncthreads();
  if(t<20){
    double s=(double)wsum[0*20+t]+(double)wsum[1*20+t]+(double)wsum[2*20+t]+(double)wsum[3*20+t];
    pnrhT[(size_t)t*PST+b]=s;
  }
}

// ------- K3: redundant {pZ/pnrhT reduce + in40 + L1} + distributed L2 -------
__global__ __launch_bounds__(256) void k_l12(
    const double* __restrict__ pZ, const double* __restrict__ pnrhT,
    const float* __restrict__ read_head,
    const float* __restrict__ aW1,const float* __restrict__ ab1,
    const float* __restrict__ mW1,const float* __restrict__ mb1,
    const float* __restrict__ aW2,const float* __restrict__ ab2,
    const float* __restrict__ mW2,const float* __restrict__ mb2,
    float* __restrict__ out, float* __restrict__ h2g, double* __restrict__ Sd){
  __shared__ float in40[40], h1s[110];
  __shared__ double dred[24];
  int t=threadIdx.x, b=blockIdx.x, wave=t>>6, lane=t&63;
  int net=(b>=48);
  for(int j=wave; j<22; j+=4){
    double s=0.0;
    if(j<20){
      const double* src=pnrhT+(size_t)j*PST;
      for(int idx=lane; idx<NB; idx+=64) s+=src[idx];
    } else {
      for(int idx=lane; idx<NB; idx+=64) s+=pZ[2*idx+(j-20)];
    }
    for(int off=32;off>0;off>>=1) s+=__shfl_down(s,off,64);
    if(lane==0) dred[j]=s;
  }
  __syncthreads();
  if(t<20){
    double Zr=dred[20]+1e-16;
    float nv=(float)(dred[t]/Zr);
    in40[20+t]=nv; in40[t]=read_head[t];
    if(b==0) out[NRH_OFF+t]=nv;
  }
  if(b==0 && t==21){ Sd[0]=dred[20]; Sd[1]=dred[21]; }
  __syncthreads();
  int g=t>>4, l16=t&15;
  const float* W1=net?mW1:aW1; const float* B1=net?mb1:ab1;
  for(int pass=0; pass<7; ++pass){
    int r=pass*16+g;
    if(r<110){
      const float* w=W1+(size_t)r*40;
      float a=0.f;
      for(int c=l16;c<40;c+=16) a+=w[c]*in40[c];
      a+=__shfl_xor(a,8,64); a+=__shfl_xor(a,4,64); a+=__shfl_xor(a,2,64); a+=__shfl_xor(a,1,64);
      if(l16==0) h1s[r]=fmaxf(a+B1[r],0.f);
    }
  }
  __syncthreads();
  int r=(b-net*48)*4+wave;
  if(r<190){
    const float* w=(net?mW2:aW2)+(size_t)r*110;
    float a=0.f;
    for(int c=lane;c<110;c+=64) a+=w[c]*h1s[c];
    for(int off=32;off>0;off>>=1) a+=__shfl_down(a,off,64);
    if(lane==0) h2g[net*190+r]=fmaxf(a+(net?mb2:ab2)[r],0.f);
  }
}

// ------- K4: L3 distributed -------
__global__ __launch_bounds__(256) void k_l3(const float* __restrict__ h2g,
    const float* __restrict__ aW3,const float* __restrict__ ab3,
    const float* __restrict__ mW3,const float* __restrict__ mb3,
    float* __restrict__ h3g){
  int t=threadIdx.x, b=blockIdx.x, wave=t>>6, lane=t&63;
  int net=(b>=68);
  int r=(b-net*68)*4+wave;
  if(r>=270) return;
  const float* w=(net?mW3:aW3)+(size_t)r*190;
  const float* in=h2g+net*190;
  float a=0.f;
  for(int c=lane;c<190;c+=64) a+=w[c]*in[c];
  for(int off=32;off>0;off>>=1) a+=__shfl_down(a,off,64);
  if(lane==0) h3g[net*270+r]=fmaxf(a+(net?mb3:ab3)[r],0.f);
}

// ------- K5: L4 distributed -------
__global__ __launch_bounds__(256) void k_l4(const float* __restrict__ h3g,
    const float* __restrict__ aW4,const float* __restrict__ ab4,
    const float* __restrict__ mW4,const float* __restrict__ mb4,
    float* __restrict__ h4g){
  int t=threadIdx.x, b=blockIdx.x, wave=t>>6, lane=t&63;
  int net=(b>=82);
  int r=(b-net*82)*4+wave;
  if(r>=325) return;
  const float* w=(net?mW4:aW4)+(size_t)r*270;
  const float* in=h3g+net*270;
  float a=0.f;
  for(int c=lane;c<270;c+=64) a+=w[c]*in[c];
  for(int off=32;off>0;off>>=1) a+=__shfl_down(a,off,64);
  if(lane==0) h4g[net*325+r]=a+(net?mb4:ab4)[r];
}

// ------- K6: fin, 21 blocks: redundant dual softmax; blocks 0-19 one Wv row; block 20 writes out -------
__global__ __launch_bounds__(256) void k_fin(const float* __restrict__ h4g,
    const float* __restrict__ Wv, const float* __restrict__ bv,
    float* __restrict__ P, float* __restrict__ out){
  __shared__ float red[256], outv[325], sc[2];
  int t=threadIdx.x, b=blockIdx.x;
  // net A softmax (325 elems over 256 threads: t and 256+t)
  float a0=h4g[t], a1=(t<69)?h4g[256+t]:-3.0e38f;
  red[t]=fmaxf(a0,a1); __syncthreads();
  for(int o=128;o>0;o>>=1){ if(t<o) red[t]=fmaxf(red[t],red[t+o]); __syncthreads(); }
  if(t==0) sc[0]=red[0]; __syncthreads();
  float ea0=expf(a0-sc[0]), ea1=(t<69)?expf(a1-sc[0]):0.f;
  red[t]=ea0+ea1; __syncthreads();
  for(int o=128;o>0;o>>=1){ if(t<o) red[t]+=red[t+o]; __syncthreads(); }
  if(t==0) sc[1]=red[0]; __syncthreads();
  float sA=sc[1];
  float pA0=ea0/sA, pA1=ea1/sA;
  __syncthreads();
  // net M softmax
  float m0=h4g[325+t], m1=(t<69)?h4g[325+256+t]:-3.0e38f;
  red[t]=fmaxf(m0,m1); __syncthreads();
  for(int o=128;o>0;o>>=1){ if(t<o) red[t]=fmaxf(red[t],red[t+o]); __syncthreads(); }
  if(t==0) sc[0]=red[0]; __syncthreads();
  float em0=expf(m0-sc[0]), em1=(t<69)?expf(m1-sc[0]):0.f;
  red[t]=em0+em1; __syncthreads();
  for(int o=128;o>0;o>>=1){ if(t<o) red[t]+=red[t+o]; __syncthreads(); }
  if(t==0) sc[1]=red[0]; __syncthreads();
  float sM=sc[1];
  float ah0=P[105], ah1=P[106];
  outv[t]=ah0*pA0+ah1*(em0/sM);
  if(t<69) outv[256+t]=ah0*pA1+ah1*(em1/sM);
  __syncthreads();
  if(b==20){
    out[OUT_OFF+t]=outv[t];
    if(t<69) out[OUT_OFF+256+t]=outv[256+t];
  } else {
    const float* w=Wv+(size_t)b*325;
    float a=w[t]*outv[t];
    if(t<69) a+=w[256+t]*outv[256+t];
    red[t]=a; __syncthreads();
    for(int o=128;o>0;o>>=1){ if(t<o) red[t]+=red[t+o]; __syncthreads(); }
    if(t==0){
      float rho=P[104];
      P[112+b]=rho*P[84+b]+(1.0f-rho)*(red[0]+bv[b]);
    }
  }
}

// ------- K7: normalize rw/ww in place + new_memory (clean, R4 version) -------
__global__ __launch_bounds__(256) void k_memupd(const float* __restrict__ M,
                         float* __restrict__ w_r, float* __restrict__ w_w,
                         const float* __restrict__ P, const double* __restrict__ Sd,
                         float* __restrict__ nm){
  __shared__ float4 ld[1280];
  int t=threadIdx.x, b=blockIdx.x;
  float er[20], af[20];
#pragma unroll
  for(int j=0;j<20;j++){ er[j]=P[64+j]; af[j]=P[112+j]; }
  float Zr=(float)Sd[0]+1e-16f, Zw=(float)Sd[1]+1e-16f;
  const float4* Mf4=(const float4*)M;
  float4* nmf4=(float4*)nm;
  for(int p=0;p<4;p++){
    int rb=b*1024+p*256;
    size_t f4b=(size_t)rb*5;
#pragma unroll
    for(int k=0;k<5;k++){
      size_t idx=f4b+(size_t)(k*256+t);
      if(idx<NF4) ld[k*256+t]=Mf4[idx];
    }
    __syncthreads();
    int i=rb+t;
    if(i<NN){
      float wrn=w_r[i]/Zr;
      float wwn=w_w[i]/Zw;
      w_r[i]=wrn; w_w[i]=wwn;
#pragma unroll
      for(int q=0;q<5;q++){
        float4 v=ld[t*5+q];
        float4 o;
        o.x=v.x*(1.0f-wwn*er[4*q+0])+wwn*af[4*q+0];
        o.y=v.y*(1.0f-wwn*er[4*q+1])+wwn*af[4*q+1];
        o.z=v.z*(1.0f-wwn*er[4*q+2])+wwn*af[4*q+2];
        o.w=v.w*(1.0f-wwn*er[4*q+3])+wwn*af[4*q+3];
        ld[t*5+q]=o;
      }
    }
    __syncthreads();
#pragma unroll
    for(int k=0;k<5;k++){
      size_t idx=f4b+(size_t)(k*256+t);
      if(idx<NF4) nmf4[idx]=ld[k*256+t];
    }
    __syncthreads();
  }
}

extern "C" void kernel_launch(void* const* d_in, const int* in_sizes, int n_in,
                              void* d_out, int out_size, void* d_ws, size_t ws_size,
                              hipStream_t stream) {
  const float* X    =(const float*)d_in[0];
  const float* rwp  =(const float*)d_in[1];
  const float* wwp  =(const float*)d_in[2];
  const float* Mem  =(const float*)d_in[3];
  const float* rhd  =(const float*)d_in[4];
  const float* W1   =(const float*)d_in[5];
  const float* b1   =(const float*)d_in[6];
  const float* W2   =(const float*)d_in[7];
  const float* b2   =(const float*)d_in[8];
  const float* Wxi  =(const float*)d_in[9];
  const float* bxi  =(const float*)d_in[10];
  const float* Wz   =(const float*)d_in[11];
  const float* bz   =(const float*)d_in[12];
  const float* Wv   =(const float*)d_in[13];
  const float* bv   =(const float*)d_in[14];
  const float* aW1  =(const float*)d_in[15];
  const float* ab1  =(const float*)d_in[16];
  const float* aW2  =(const float*)d_in[17];
  const float* ab2  =(const float*)d_in[18];
  const float* aW3  =(const float*)d_in[19];
  const float* ab3  =(const float*)d_in[20];
  const float* aW4  =(const float*)d_in[21];
  const float* ab4  =(const float*)d_in[22];
  const float* mW1  =(const float*)d_in[23];
  const float* mb1  =(const float*)d_in[24];
  const float* mW2  =(const float*)d_in[25];
  const float* mb2  =(const float*)d_in[26];
  const float* mW3  =(const float*)d_in[27];
  const float* mb3  =(const float*)d_in[28];
  const float* mW4  =(const float*)d_in[29];
  const float* mb4  =(const float*)d_in[30];

  float* out = (float*)d_out;
  char* ws = (char*)d_ws;
  float*  P   = (float*)(ws + 0);        // 256 floats
  double* Sd  = (double*)(ws + 2048);    // Z_r, Z_w
  float*  h2g = (float*)(ws + 4096);     // 380
  float*  h3g = (float*)(ws + 8192);     // 540
  float*  h4g = (float*)(ws + 12288);    // 650
  float4* pms = (float4*)(ws + 16384);   // NB float4 (~15.6 KB)
  double* pZ  = (double*)(ws + 65536);   // NB*2 (~15.6 KB)
  double* pnrhT=(double*)(ws + 131072);  // 20*PST doubles (160 KB)

  float2* sc2 = (float2*)(out + NM_OFF);   // scores staged in dead nm region
  float*  w_r = out + RW_OFF;              // unnormalized until k_memupd
  float*  w_w = out + WW_OFF;
  float*  nm  = out + NM_OFF;

  k_scores<<<NB,256,0,stream>>>(X,W1,b1,W2,b2,Wxi,bxi,Wz,bz,Mem,P,sc2,pms);
  k_shift<<<NB,256,0,stream>>>(sc2,rwp,wwp,Mem,P,pms,w_r,w_w,pZ,pnrhT);
  k_l12<<<96,256,0,stream>>>(pZ,pnrhT,rhd,aW1,ab1,mW1,mb1,aW2,ab2,mW2,mb2,out,h2g,Sd);
  k_l3<<<136,256,0,stream>>>(h2g,aW3,ab3,mW3,mb3,h3g);
  k_l4<<<164,256,0,stream>>>(h3g,aW4,ab4,mW4,mb4,h4g);
  k_fin<<<21,256,0,stream>>>(h4g,Wv,bv,P,out);
  k_memupd<<<NB,256,0,stream>>>(Mem,w_r,w_w,P,Sd,nm);
}